// Round 21
// baseline (136.836 us; speedup 1.0000x reference)
//
#include <hip/hip_runtime.h>

#define NH 16
#define DH 64
#define SEQ 512
#define SIN 64
#define NBATCH 8

#define L2E 1.4426950408889634f          // log2(e)
#define C2  0.18033688011112043f         // 0.125 * log2(e)
#define DEFER_THR 11.5412435f            // 8 * log2(e)

typedef short bf16x8 __attribute__((ext_vector_type(8)));
typedef short bf16x4 __attribute__((ext_vector_type(4)));
typedef float f32x4 __attribute__((ext_vector_type(4)));

__device__ __forceinline__ unsigned short f2bf(float f) {
  union { float f; unsigned u; } v; v.f = f;
  unsigned r = v.u + 0x7FFFu + ((v.u >> 16) & 1u);
  return (unsigned short)(r >> 16);
}
__device__ __forceinline__ float bf2f(unsigned short b) {
  union { unsigned u; float f; } v; v.u = ((unsigned)b) << 16;
  return v.f;
}
// e5m2 fp8 (= truncated f16): encode with RNE, decode via bit-expansion.
__device__ __forceinline__ unsigned f2e5m2(float f) {
  union { _Float16 h; unsigned short u; } cv; cv.h = (_Float16)f;
  const unsigned short t = cv.u;
  return ((unsigned)(t + 0x7Fu + ((t >> 8) & 1u)) >> 8) & 0xFFu;
}
__device__ __forceinline__ float e5m22f(unsigned b) {
  union { unsigned u; float f; } dv;
  dv.u = ((b & 0x80u) << 24) | (((b & 0x7Fu) << 21) + 0x38000000u);
  return dv.f;
}
__device__ __forceinline__ f32x4 mfma16(bf16x8 a, bf16x8 b, f32x4 c) {
  return __builtin_amdgcn_mfma_f32_16x16x32_bf16(a, b, c, 0, 0, 0);
}
__device__ __forceinline__ void gload_lds16(const unsigned short* g, unsigned short* l) {
  __builtin_amdgcn_global_load_lds((const __attribute__((address_space(1))) void*)g,
                                   (__attribute__((address_space(3))) void*)l, 16, 0, 0);
}

// 64x64 bf16 tile in LDS, logical [64][64], physical byte swizzle
// phys = row*128 + (colbyte ^ ((row&7)<<4)); staged with pre-swizzled global src.
__device__ __forceinline__ void stage_tile_swz(const unsigned short* g, int gstride,
                                               unsigned short* lds, int w, int lane) {
  #pragma unroll
  for (int c = 0; c < 2; ++c) {
    const int row = w * 16 + c * 8 + (lane >> 3);
    const int cb = ((lane & 7) ^ (lane >> 3)) << 4;
    gload_lds16(g + (size_t)row * gstride + (cb >> 1),
                lds + (w * 16 + c * 8) * 64);
  }
}
__device__ __forceinline__ bf16x8 read_swz(const unsigned short* lds, int row, int colbyte) {
  return *(const bf16x8*)((const char*)(lds + row * 64) + (colbyte ^ ((row & 7) << 4)));
}
// same swizzle for 128-byte rows (BK=64 staging in k_gemm)
__device__ __forceinline__ bf16x8 read_swz128(const unsigned short* lds, int row, int colbyte) {
  return *(const bf16x8*)((const char*)lds + row * 128 + (colbyte ^ ((row & 7) << 4)));
}

// ---------------- merged convert kernel ----------------
__global__ __launch_bounds__(256) void k_convert_all(const float* __restrict__ hs,
                                                     const float* __restrict__ ihs,
                                                     const float* __restrict__ de,
                                                     const float* __restrict__ Wq,
                                                     const float* __restrict__ Wk,
                                                     const float* __restrict__ Wv,
                                                     unsigned short* __restrict__ X,
                                                     unsigned short* __restrict__ E,
                                                     unsigned short* __restrict__ Wt) {
  __shared__ float t[64][65];
  const int bx = blockIdx.x, tid = threadIdx.x;
  if (bx < 4608) {
    int idx = bx * 256 + tid;
    float4 v;
    if (idx < 1048576) v = ((const float4*)hs)[idx];
    else               v = ((const float4*)ihs)[idx - 1048576];
    ushort4 o; o.x = f2bf(v.x); o.y = f2bf(v.y); o.z = f2bf(v.z); o.w = f2bf(v.w);
    ((ushort4*)X)[idx] = o;
  } else if (bx < 5376) {
    const int wb = bx - 4608;
    const int z = wb >> 8, rem = wb & 255;
    const float* W = (z == 0) ? Wq : (z == 1) ? Wk : Wv;
    const int n0 = (rem & 15) * 64, k0 = (rem >> 4) * 64;
    #pragma unroll
    for (int q = 0; q < 4; ++q) {
      int s = q * 256 + tid;
      int r = s >> 4, c4 = s & 15;
      float4 v = *(const float4*)(W + (size_t)(k0 + r) * 1024 + n0 + c4 * 4);
      t[r][c4 * 4 + 0] = v.x; t[r][c4 * 4 + 1] = v.y;
      t[r][c4 * 4 + 2] = v.z; t[r][c4 * 4 + 3] = v.w;
    }
    __syncthreads();
    #pragma unroll
    for (int q = 0; q < 4; ++q) {
      int s = q * 256 + tid;
      int rn = s >> 4, c4 = s & 15;
      ushort4 o;
      o.x = f2bf(t[c4 * 4 + 0][rn]); o.y = f2bf(t[c4 * 4 + 1][rn]);
      o.z = f2bf(t[c4 * 4 + 2][rn]); o.w = f2bf(t[c4 * 4 + 3][rn]);
      *(ushort4*)(Wt + ((size_t)(z << 10) + n0 + rn) * 1024 + k0 + c4 * 4) = o;
    }
  } else {
    int idx = (bx - 5376) * 256 + tid;
    ushort4 o;
    if (idx < 16368) {
      float4 v = ((const float4*)de)[idx];
      o.x = f2bf(v.x); o.y = f2bf(v.y); o.z = f2bf(v.z); o.w = f2bf(v.w);
    } else { o.x = 0; o.y = 0; o.z = 0; o.w = 0; }
    ((ushort4*)E)[idx] = o;
  }
}

// ---------------- fused QKV GEMM (256x256, 8 waves, BK=64, swizzled staging) ----------------
// XCD-swizzled block mapping: 216 blocks = 8 XCDs x 27 (bijective chunked).
__global__ __launch_bounds__(512) void k_gemm(const unsigned short* __restrict__ X,
                                              const unsigned short* __restrict__ Wt,
                                              const float* __restrict__ bq,
                                              const float* __restrict__ bk,
                                              const float* __restrict__ bv,
                                              unsigned short* __restrict__ Q,
                                              unsigned short* __restrict__ K,
                                              unsigned short* __restrict__ Vt,
                                              unsigned short* __restrict__ IK,
                                              unsigned short* __restrict__ IVt) {
  __shared__ unsigned short smem[65536];   // A[2]@0 (2x32KB), B[2]@32768; epilogue reuses all
  const int tid = threadIdx.x, lane = tid & 63, w = tid >> 6;
  const int lg = lane >> 4, lc = lane & 15;
  const int bid = blockIdx.x + 12 * blockIdx.y;
  const int swz = (bid & 7) * 27 + (bid >> 3);          // 216 = 8*27
  const int m0 = (swz / 12) * 256, n0 = (swz % 12) * 256;
  const int wr = w >> 2, wc = w & 3;
  const int which = n0 >> 10;
  const int h0 = (n0 & 1023) >> 6;
  const float* barr = (which == 0) ? bq : (which == 1) ? bk : bv;

  f32x4 acc[8][4];
  #pragma unroll
  for (int i = 0; i < 8; ++i)
    #pragma unroll
    for (int j = 0; j < 4; ++j) acc[i][j] = (f32x4){0.f, 0.f, 0.f, 0.f};

  const unsigned short* ap[4];
  const unsigned short* bp[4];
  #pragma unroll
  for (int q = 0; q < 4; ++q) {
    const int c = (w * 4 + q) * 64 + lane;
    const int row = c >> 3, cc = c & 7;
    const int sc = (cc ^ (row & 7)) * 8;
    ap[q] = X  + (size_t)(m0 + row) * 1024 + sc;
    bp[q] = Wt + (size_t)(n0 + row) * 1024 + sc;
  }

  #define STAGE(bi)                                                        \
    {                                                                      \
      _Pragma("unroll")                                                    \
      for (int q_ = 0; q_ < 4; ++q_) {                                     \
        gload_lds16(ap[q_], smem + (bi) * 16384 + ((w * 4 + q_) * 64) * 8);\
        gload_lds16(bp[q_], smem + 32768 + (bi) * 16384 + ((w * 4 + q_) * 64) * 8); \
        ap[q_] += 64; bp[q_] += 64;                                        \
      }                                                                    \
    }

  STAGE(0);
  int cur = 0;
  for (int kt = 0; kt < 16; ++kt) {
    __syncthreads();
    if (kt + 1 < 16) STAGE(cur ^ 1);
    const unsigned short* A = smem + cur * 16384;
    const unsigned short* B = smem + 32768 + cur * 16384;
    #pragma unroll
    for (int kc = 0; kc < 2; ++kc) {
      bf16x8 af[8], bfr[4];
      #pragma unroll
      for (int i = 0; i < 8; ++i)
        af[i] = read_swz128(A, wr * 128 + i * 16 + lc, kc * 64 + lg * 16);
      #pragma unroll
      for (int j = 0; j < 4; ++j)
        bfr[j] = read_swz128(B, wc * 64 + j * 16 + lc, kc * 64 + lg * 16);
      __builtin_amdgcn_s_setprio(1);
      #pragma unroll
      for (int i = 0; i < 8; ++i)
        #pragma unroll
        for (int j = 0; j < 4; ++j)
          acc[i][j] = mfma16(af[i], bfr[j], acc[i][j]);
      __builtin_amdgcn_s_setprio(0);
    }
    cur ^= 1;
  }
  #undef STAGE

  __syncthreads();
  {
    char* Cs = (char*)smem;
    #pragma unroll
    for (int j = 0; j < 4; ++j) {
      const float bias = barr[(n0 & 1023) + wc * 64 + j * 16 + lc];
      #pragma unroll
      for (int i = 0; i < 8; ++i)
        #pragma unroll
        for (int ii = 0; ii < 4; ++ii) {
          int row = wr * 128 + i * 16 + lg * 4 + ii;
          int col = wc * 64 + j * 16 + lc;
          if (which == 2) { int t = row; row = col; col = t; }
          *(unsigned short*)(Cs + row * 512 + ((col * 2) ^ (((row >> 2) & 31) << 4))) =
              f2bf(acc[i][j][ii] + bias);
        }
    }
  }
  __syncthreads();
  {
    const char* Cs = (const char*)smem;
    const int row = tid >> 1;
    #pragma unroll
    for (int rnd = 0; rnd < 2; ++rnd) {
      const int q = (tid & 1) + rnd * 2;
      uint4 cvec[8];
      #pragma unroll
      for (int c8 = 0; c8 < 8; ++c8)
        cvec[c8] = *(const uint4*)(Cs + row * 512 +
                                   ((q * 128 + c8 * 16) ^ (((row >> 2) & 31) << 4)));
      unsigned short* dst = nullptr;
      if (which != 2) {
        const int gm = m0 + row, hh = h0 + q;
        if (gm < 4096) {
          const int bb = gm >> 9, ss = gm & 511;
          unsigned short* base = (which == 0) ? Q : K;
          dst = base + (((size_t)(bb * NH + hh) * 512 + ss) << 6);
        } else if (which == 1) {
          const int mi = gm - 4096, bb = mi >> 6, si = mi & 63;
          dst = IK + (((size_t)(bb * NH + hh) * 64 + si) << 6);
        }
      } else {
        const int dd = row, hh = h0 + (dd >> 6), ddl = dd & 63;
        const int gm0 = m0 + q * 64;
        if (gm0 < 4096) {
          const int bb = gm0 >> 9, ss0 = gm0 & 511;
          dst = Vt + ((size_t)(bb * NH + hh) * 64 + ddl) * 512 + ss0;
        } else {
          const int mi0 = gm0 - 4096, bb = mi0 >> 6;
          dst = IVt + (((size_t)(bb * NH + hh) * 64 + ddl) << 6);
        }
      }
      if (dst) {
        #pragma unroll
        for (int c8 = 0; c8 < 8; ++c8)
          *(uint4*)(dst + c8 * 8) = cvec[c8];
      }
    }
  }
}

// ---------------- bias tile kernel (v5: fp8 e5m2 output, transposed tables) ----------------
// Tables stored [128 u][64 row], physical col = row ^ ((u&7)<<3).  Output tile
// in MFMA C-fragment order, fp8 e5m2 (4096 B/tile), uint-packed stores.
__global__ __launch_bounds__(256) void k_bias(const unsigned short* __restrict__ Qg,
                                              const unsigned short* __restrict__ Kg,
                                              const unsigned short* __restrict__ Eg,
                                              const float* __restrict__ mask,
                                              unsigned char* __restrict__ Bias) {
  const int rt = blockIdx.x, lt = blockIdx.y, bh = blockIdx.z;
  const int l0 = lt * 64, r0 = rt * 64;
  const int p0 = l0 - r0 + 448;
  const int tid = threadIdx.x, lane = tid & 63, w = tid >> 6;
  const int lg = lane >> 4, lc = lane & 15;
  const int ubase = w * 32;
  const int b = bh >> 4;

  __shared__ unsigned short smem[16384];     // 32 KB
  unsigned short* Qs  = smem;                // phase A: 8 KB
  unsigned short* Ks  = smem + 4096;         // phase A: 8 KB
  unsigned short* qdl = smem + 8192;         // 16 KB, [128][64] (persistent)
  unsigned short* kdl = smem;                // phase B: 16 KB over Qs+Ks

  stage_tile_swz(Qg + ((size_t)(bh * 512 + l0)) * 64, 64, Qs, w, lane);
  stage_tile_swz(Kg + ((size_t)(bh * 512 + r0)) * 64, 64, Ks, w, lane);

  bf16x8 eb[2][2];
  #pragma unroll
  for (int ns = 0; ns < 2; ++ns) {
    const int u = ubase + ns * 16 + lc;
    const unsigned short* ep = Eg + (size_t)(p0 + u) * 64 + lg * 8;
    eb[ns][0] = *(const bf16x8*)(ep);
    eb[ns][1] = *(const bf16x8*)(ep + 32);
  }
  __syncthreads();    // staging complete

  f32x4 da[4][2];
  // qd: MFMAs over Qs -> qdl (disjoint region)
  #pragma unroll
  for (int ms = 0; ms < 4; ++ms) { da[ms][0] = (f32x4){0,0,0,0}; da[ms][1] = (f32x4){0,0,0,0}; }
  #pragma unroll
  for (int kc = 0; kc < 2; ++kc)
    #pragma unroll
    for (int ms = 0; ms < 4; ++ms) {
      bf16x8 a = read_swz(Qs, ms * 16 + lc, kc * 64 + lg * 16);
      da[ms][0] = mfma16(a, eb[0][kc], da[ms][0]);
      da[ms][1] = mfma16(a, eb[1][kc], da[ms][1]);
    }
  #pragma unroll
  for (int ns = 0; ns < 2; ++ns) {
    const int u = ubase + ns * 16 + lc;
    const int k = (u & 7) << 3;
    #pragma unroll
    for (int ms = 0; ms < 4; ++ms) {
      ushort4 o;
      o.x = f2bf(da[ms][ns][0]); o.y = f2bf(da[ms][ns][1]);
      o.z = f2bf(da[ms][ns][2]); o.w = f2bf(da[ms][ns][3]);
      *(ushort4*)(qdl + u * 64 + ((ms * 16 + lg * 4) ^ k)) = o;
    }
  }
  // kd: MFMAs over Ks, held in regs across the barrier
  #pragma unroll
  for (int ms = 0; ms < 4; ++ms) { da[ms][0] = (f32x4){0,0,0,0}; da[ms][1] = (f32x4){0,0,0,0}; }
  #pragma unroll
  for (int kc = 0; kc < 2; ++kc)
    #pragma unroll
    for (int ms = 0; ms < 4; ++ms) {
      bf16x8 a = read_swz(Ks, ms * 16 + lc, kc * 64 + lg * 16);
      da[ms][0] = mfma16(a, eb[0][kc], da[ms][0]);
      da[ms][1] = mfma16(a, eb[1][kc], da[ms][1]);
    }
  __syncthreads();    // Qs/Ks reads done; safe to overwrite with kdl
  #pragma unroll
  for (int ns = 0; ns < 2; ++ns) {
    const int u = ubase + ns * 16 + lc;
    const int k = (u & 7) << 3;
    #pragma unroll
    for (int ms = 0; ms < 4; ++ms) {
      ushort4 o;
      o.x = f2bf(da[ms][ns][0]); o.y = f2bf(da[ms][ns][1]);
      o.z = f2bf(da[ms][ns][2]); o.w = f2bf(da[ms][ns][3]);
      *(ushort4*)(kdl + u * 64 + ((ms * 16 + lg * 4) ^ k)) = o;
    }
  }
  __syncthreads();    // tables visible

  {
    unsigned char* dst = Bias + ((size_t)(bh * 64 + lt * 8 + rt)) * 4096;
    #pragma unroll
    for (int ns = 0; ns < 4; ++ns) {
      const int ri = ns * 16 + lc;
      const float mk2 = mask[b * SEQ + r0 + ri] * L2E;
      unsigned ob = 0;
      #pragma unroll
      for (int i = 0; i < 4; ++i) {
        const int li = w * 16 + lg * 4 + i;
        const int uq = li - ri + 63;
        const int k = (uq & 7) << 3;
        const float qv = bf2f(qdl[uq * 64 + (li ^ k)]);
        const float kv = bf2f(kdl[uq * 64 + (ri ^ k)]);
        ob |= f2e5m2((qv + kv) * C2 + mk2) << (8 * i);
      }
      *(unsigned*)(dst + (w * 4 + ns) * 256 + lane * 4) = ob;
    }
  }
}

// ---------------- fused attention ----------------
// flash, dbuf K/V, fp8 reg bias, exp2 softmax, lazy-max defer, ones-MFMA denominators.
__global__ __launch_bounds__(256) void k_attn(const unsigned short* __restrict__ Qg,
                                              const unsigned short* __restrict__ Kg,
                                              const unsigned short* __restrict__ Vtg,
                                              const unsigned short* __restrict__ IKg,
                                              const unsigned short* __restrict__ IVtg,
                                              const unsigned char* __restrict__ Bias,
                                              const float* __restrict__ imask,
                                              const float* __restrict__ gate,
                                              float* __restrict__ out) {
  const int lt = blockIdx.x, h = blockIdx.y, b = blockIdx.z;
  const int l0 = lt * 64;
  const int tid = threadIdx.x;
  const int lane = tid & 63, w = tid >> 6;
  const int lg = lane >> 4, lc = lane & 15;
  const int bh = b * NH + h;
  const short ob = (short)0x3F80;
  const bf16x8 ONES = {ob, ob, ob, ob, ob, ob, ob, ob};

  __shared__ unsigned short Ks[2 * 64 * 64];
  __shared__ unsigned short Vts[2 * 64 * 64];
  __shared__ unsigned short Ps[64 * 64];

  bf16x8 qa[2];
  {
    const unsigned short* qrow = Qg + ((size_t)(bh * 512 + l0 + w * 16 + lc)) * 64;
    qa[0] = *(const bf16x8*)(qrow + lg * 8);
    qa[1] = *(const bf16x8*)(qrow + 32 + lg * 8);
  }

  f32x4 oacc[4];
  #pragma unroll
  for (int i = 0; i < 4; ++i) oacc[i] = (f32x4){0.f, 0.f, 0.f, 0.f};
  float mrun[4], lrun[4];
  #pragma unroll
  for (int i = 0; i < 4; ++i) { mrun[i] = -3.0e38f; lrun[i] = 0.f; }

  stage_tile_swz(Kg + ((size_t)(bh * 512)) * 64, 64, Ks, w, lane);
  stage_tile_swz(Vtg + (size_t)bh * 64 * 512, 512, Vts, w, lane);
  const unsigned char* btbase = Bias + ((size_t)(bh * 64 + lt * 8)) * 4096;
  unsigned brow[4];
  #pragma unroll
  for (int ns = 0; ns < 4; ++ns)
    brow[ns] = *(const unsigned*)(btbase + (w * 4 + ns) * 256 + lane * 4);

  for (int rt = 0; rt < 8; ++rt) {
    const int r0 = rt * 64;
    const int cur = rt & 1;
    __syncthreads();

    if (rt < 7) {
      stage_tile_swz(Kg + ((size_t)(bh * 512 + r0 + 64)) * 64, 64, Ks + (cur ^ 1) * 4096, w, lane);
      stage_tile_swz(Vtg + (size_t)bh * 64 * 512 + r0 + 64, 512, Vts + (cur ^ 1) * 4096, w, lane);
    } else {
      stage_tile_swz(IKg + (size_t)bh * 4096, 64, Ks, w, lane);
      stage_tile_swz(IVtg + (size_t)bh * 4096, 64, Vts, w, lane);
    }
    unsigned bnext[4];
    if (rt < 7) {
      const unsigned char* bt = btbase + (size_t)(rt + 1) * 4096;
      #pragma unroll
      for (int ns = 0; ns < 4; ++ns)
        bnext[ns] = *(const unsigned*)(bt + (w * 4 + ns) * 256 + lane * 4);
    }

    const unsigned short* Kc = Ks + cur * 4096;
    const unsigned short* Vc = Vts + cur * 4096;

    f32x4 sacc[4];
    #pragma unroll
    for (int ns = 0; ns < 4; ++ns) sacc[ns] = (f32x4){0.f, 0.f, 0.f, 0.f};
    __builtin_amdgcn_s_setprio(1);
    #pragma unroll
    for (int kc = 0; kc < 2; ++kc)
      #pragma unroll
      for (int ns = 0; ns < 4; ++ns) {
        bf16x8 kb = read_swz(Kc, ns * 16 + lc, kc * 64 + lg * 16);
        sacc[ns] = mfma16(qa[kc], kb, sacc[ns]);
      }
    __builtin_amdgcn_s_setprio(0);
    float sv[4][4];
    #pragma unroll
    for (int ns = 0; ns < 4; ++ns)
      #pragma unroll
      for (int i = 0; i < 4; ++i)
        sv[ns][i] = fmaf(sacc[ns][i], C2, e5m22f((brow[ns] >> (8 * i)) & 0xFFu));

    float mt[4];
    #pragma unroll
    for (int i = 0; i < 4; ++i)
      mt[i] = fmaxf(fmaxf(sv[0][i], sv[1][i]), fmaxf(sv[2][i], sv[3][i]));
    bool need = false;
    #pragma unroll
    for (int i = 0; i < 4; ++i) need = need || (mt[i] > mrun[i] + DEFER_THR);
    if (__any(need)) {
      #pragma unroll
      for (int i = 0; i < 4; ++i) {
        float m_ = mt[i];
        #pragma unroll
        for (int m = 1; m <= 8; m <<= 1) m_ = fmaxf(m_, __shfl_xor(m_, m));
        const float mnew = fmaxf(mrun[i], m_);
        const float fr = exp2f(mrun[i] - mnew);
        mrun[i] = mnew;
        lrun[i] *= fr;
        #pragma unroll
        for (int ds = 0; ds < 4; ++ds) oacc[ds][i] *= fr;
      }
    }
    #pragma unroll
    for (int ns = 0; ns < 4; ++ns)
      #pragma unroll
      for (int i = 0; i < 4; ++i)
        sv[ns][i] = exp2f(sv[ns][i] - mrun[i]);
    #pragma unroll
    for (int ns = 0; ns < 4; ++ns)
      #pragma unroll
      for (int i = 0; i < 4; ++i) {
        const int row = w * 16 + lg * 4 + i;
        const int cb = (ns * 16 + lc) * 2;
        *(unsigned short*)((char*)Ps + row * 128 + (cb ^ ((row & 7) << 4))) = f2bf(sv[ns][i]);
      }
    f32x4 lsum = (f32x4){0.f, 0.f, 0.f, 0.f};
    __builtin_amdgcn_s_setprio(1);
    #pragma unroll
    for (int kc = 0; kc < 2; ++kc) {
      bf16x8 pa = read_swz(Ps, w * 16 + lc, kc * 64 + lg * 16);
      lsum = mfma16(pa, ONES, lsum);
      #pragma unroll
      for (int ds = 0; ds < 4; ++ds) {
        bf16x8 vb = read_swz(Vc, ds * 16 + lc, kc * 64 + lg * 16);
        oacc[ds] = mfma16(pa, vb, oacc[ds]);
      }
    }
    __builtin_amdgcn_s_setprio(0);
    #pragma unroll
    for (int i = 0; i < 4; ++i) lrun[i] += lsum[i];
    if (rt < 7) {
      #pragma unroll
      for (int ns = 0; ns < 4; ++ns) brow[ns] = bnext[ns];
    }
  }

  // ---- instruct branch ----
  {
    __syncthreads();
    f32x4 sacc[4];
    #pragma unroll
    for (int ns = 0; ns < 4; ++ns) sacc[ns] = (f32x4){0.f, 0.f, 0.f, 0.f};
    #pragma unroll
    for (int kc = 0; kc < 2; ++kc)
      #pragma unroll
      for (int ns = 0; ns < 4; ++ns) {
        bf16x8 kb = read_swz(Ks, ns * 16 + lc, kc * 64 + lg * 16);
        sacc[ns] = mfma16(qa[kc], kb, sacc[ns]);
      }
    float sv[4][4];
    #pragma unroll
    for (int ns = 0; ns < 4; ++ns) {
      const float mk2 = imask[b * SIN + ns * 16 + lc] * L2E;
      #pragma unroll
      for (int i = 0; i < 4; ++i) sv[ns][i] = fmaf(sacc[ns][i], C2, mk2);
    }
    #pragma unroll
    for (int i = 0; i < 4; ++i) {
      float mt = fmaxf(fmaxf(sv[0][i], sv[1][i]), fmaxf(sv[2][i], sv[3][i]));
      #pragma unroll
      for (int m = 1; m <= 8; m <<= 1) mt = fmaxf(mt, __shfl_xor(mt, m));
      #pragma unroll
      for (int ns = 0; ns < 4; ++ns) sv[ns][i] = exp2f(sv[ns][i] - mt);
    }
    #pragma unroll
    for (int ns = 0; ns < 4; ++ns)
      #pragma unroll
      for (int i = 0; i < 4; ++i) {
        const int row = w * 16 + lg * 4 + i;
        const int cb = (ns * 16 + lc) * 2;
        *(unsigned short*)((char*)Ps + row * 128 + (cb ^ ((row & 7) << 4))) = f2bf(sv[ns][i]);
      }
    f32x4 iacc[4];
    #pragma unroll
    for (int ds = 0; ds < 4; ++ds) iacc[ds] = (f32x4){0.f, 0.f, 0.f, 0.f};
    f32x4 isum = (f32x4){0.f, 0.f, 0.f, 0.f};
    #pragma unroll
    for (int kc = 0; kc < 2; ++kc) {
      bf16x8 pa = read_swz(Ps, w * 16 + lc, kc * 64 + lg * 16);
      isum = mfma16(pa, ONES, isum);
      #pragma unroll
      for (int ds = 0; ds < 4; ++ds) {
        bf16x8 vb = read_swz(Vts, ds * 16 + lc, kc * 64 + lg * 16);
        iacc[ds] = mfma16(pa, vb, iacc[ds]);
      }
    }
    const float tg = tanhf(gate[h]);
    #pragma unroll
    for (int ds = 0; ds < 4; ++ds)
      #pragma unroll
      for (int i = 0; i < 4; ++i) {
        const int li = w * 16 + lg * 4 + i;
        const float val = oacc[ds][i] / lrun[i] + tg * (iacc[ds][i] / isum[i]);
        out[(size_t)(b * SEQ + l0 + li) * 1024 + h * 64 + ds * 16 + lc] = val;
      }
  }
}

// ---------------- launch ----------------

extern "C" void kernel_launch(void* const* d_in, const int* in_sizes, int n_in,
                              void* d_out, int out_size, void* d_ws, size_t ws_size,
                              hipStream_t stream) {
  (void)in_sizes; (void)n_in; (void)out_size; (void)ws_size;
  const float* hs    = (const float*)d_in[0];
  const float* ihs   = (const float*)d_in[1];
  const float* mask  = (const float*)d_in[2];
  const float* imask = (const float*)d_in[3];
  const float* Wq    = (const float*)d_in[4];
  const float* bq    = (const float*)d_in[5];
  const float* Wk    = (const float*)d_in[6];
  const float* bk    = (const float*)d_in[7];
  const float* Wv    = (const float*)d_in[8];
  const float* bv    = (const float*)d_in[9];
  const float* de    = (const float*)d_in[10];
  const float* gate  = (const float*)d_in[11];
  float* out = (float*)d_out;

  char* ws = (char*)d_ws;
  size_t off = 0;
  auto alloc = [&](size_t bytes) -> void* {
    void* p = ws + off;
    off += (bytes + 255) & ~(size_t)255;
    return p;
  };
  unsigned short* X    = (unsigned short*)alloc((size_t)4608 * 1024 * 2);
  unsigned short* Wt   = (unsigned short*)alloc((size_t)3072 * 1024 * 2);
  unsigned short* E    = (unsigned short*)alloc((size_t)1024 * 64 * 2);
  unsigned short* Qb   = (unsigned short*)alloc((size_t)8 * 16 * 512 * 64 * 2);
  unsigned short* Kb   = (unsigned short*)alloc((size_t)8 * 16 * 512 * 64 * 2);
  unsigned short* Vtb  = (unsigned short*)alloc((size_t)8 * 16 * 64 * 512 * 2);
  unsigned short* IKb  = (unsigned short*)alloc((size_t)8 * 16 * 64 * 64 * 2);
  unsigned short* IVtb = (unsigned short*)alloc((size_t)8 * 16 * 64 * 64 * 2);
  unsigned char* Bias  = (unsigned char*)alloc((size_t)128 * 64 * 4096);     // 32 MiB (fp8)

  k_convert_all<<<5440, 256, 0, stream>>>(hs, ihs, de, Wq, Wk, Wv, X, E, Wt);
  k_gemm<<<dim3(12, 18), 512, 0, stream>>>(X, Wt, bq, bk, bv, Qb, Kb, Vtb, IKb, IVtb);
  k_bias<<<dim3(8, 8, 128), 256, 0, stream>>>(Qb, Kb, E, mask, Bias);
  k_attn<<<dim3(8, 16, 8), 256, 0, stream>>>(Qb, Kb, Vtb, IKb, IVtb, Bias, imask, gate, out);
}

// Round 22
// 134.872 us; speedup vs baseline: 1.0146x; 1.0146x over previous
//
#include <hip/hip_runtime.h>

#define NH 16
#define DH 64
#define SEQ 512
#define SIN 64
#define NBATCH 8

#define L2E 1.4426950408889634f          // log2(e)
#define C2  0.18033688011112043f         // 0.125 * log2(e)
#define DEFER_THR 11.5412435f            // 8 * log2(e)

typedef short bf16x8 __attribute__((ext_vector_type(8)));
typedef short bf16x4 __attribute__((ext_vector_type(4)));
typedef float f32x4 __attribute__((ext_vector_type(4)));

__device__ __forceinline__ unsigned short f2bf(float f) {
  union { float f; unsigned u; } v; v.f = f;
  unsigned r = v.u + 0x7FFFu + ((v.u >> 16) & 1u);
  return (unsigned short)(r >> 16);
}
__device__ __forceinline__ float bf2f(unsigned short b) {
  union { unsigned u; float f; } v; v.u = ((unsigned)b) << 16;
  return v.f;
}
__device__ __forceinline__ f32x4 mfma16(bf16x8 a, bf16x8 b, f32x4 c) {
  return __builtin_amdgcn_mfma_f32_16x16x32_bf16(a, b, c, 0, 0, 0);
}
__device__ __forceinline__ void gload_lds16(const unsigned short* g, unsigned short* l) {
  __builtin_amdgcn_global_load_lds((const __attribute__((address_space(1))) void*)g,
                                   (__attribute__((address_space(3))) void*)l, 16, 0, 0);
}

// 64x64 bf16 tile in LDS, logical [64][64], physical byte swizzle
// phys = row*128 + (colbyte ^ ((row&7)<<4)); staged with pre-swizzled global src.
__device__ __forceinline__ void stage_tile_swz(const unsigned short* g, int gstride,
                                               unsigned short* lds, int w, int lane) {
  #pragma unroll
  for (int c = 0; c < 2; ++c) {
    const int row = w * 16 + c * 8 + (lane >> 3);
    const int cb = ((lane & 7) ^ (lane >> 3)) << 4;
    gload_lds16(g + (size_t)row * gstride + (cb >> 1),
                lds + (w * 16 + c * 8) * 64);
  }
}
__device__ __forceinline__ bf16x8 read_swz(const unsigned short* lds, int row, int colbyte) {
  return *(const bf16x8*)((const char*)(lds + row * 64) + (colbyte ^ ((row & 7) << 4)));
}
// same swizzle for 128-byte rows (BK=64 staging in k_gemm)
__device__ __forceinline__ bf16x8 read_swz128(const unsigned short* lds, int row, int colbyte) {
  return *(const bf16x8*)((const char*)lds + row * 128 + (colbyte ^ ((row & 7) << 4)));
}

// ---------------- merged convert kernel ----------------
__global__ __launch_bounds__(256) void k_convert_all(const float* __restrict__ hs,
                                                     const float* __restrict__ ihs,
                                                     const float* __restrict__ de,
                                                     const float* __restrict__ Wq,
                                                     const float* __restrict__ Wk,
                                                     const float* __restrict__ Wv,
                                                     unsigned short* __restrict__ X,
                                                     unsigned short* __restrict__ E,
                                                     unsigned short* __restrict__ Wt) {
  __shared__ float t[64][65];
  const int bx = blockIdx.x, tid = threadIdx.x;
  if (bx < 4608) {
    int idx = bx * 256 + tid;
    float4 v;
    if (idx < 1048576) v = ((const float4*)hs)[idx];
    else               v = ((const float4*)ihs)[idx - 1048576];
    ushort4 o; o.x = f2bf(v.x); o.y = f2bf(v.y); o.z = f2bf(v.z); o.w = f2bf(v.w);
    ((ushort4*)X)[idx] = o;
  } else if (bx < 5376) {
    const int wb = bx - 4608;
    const int z = wb >> 8, rem = wb & 255;
    const float* W = (z == 0) ? Wq : (z == 1) ? Wk : Wv;
    const int n0 = (rem & 15) * 64, k0 = (rem >> 4) * 64;
    #pragma unroll
    for (int q = 0; q < 4; ++q) {
      int s = q * 256 + tid;
      int r = s >> 4, c4 = s & 15;
      float4 v = *(const float4*)(W + (size_t)(k0 + r) * 1024 + n0 + c4 * 4);
      t[r][c4 * 4 + 0] = v.x; t[r][c4 * 4 + 1] = v.y;
      t[r][c4 * 4 + 2] = v.z; t[r][c4 * 4 + 3] = v.w;
    }
    __syncthreads();
    #pragma unroll
    for (int q = 0; q < 4; ++q) {
      int s = q * 256 + tid;
      int rn = s >> 4, c4 = s & 15;
      ushort4 o;
      o.x = f2bf(t[c4 * 4 + 0][rn]); o.y = f2bf(t[c4 * 4 + 1][rn]);
      o.z = f2bf(t[c4 * 4 + 2][rn]); o.w = f2bf(t[c4 * 4 + 3][rn]);
      *(ushort4*)(Wt + ((size_t)(z << 10) + n0 + rn) * 1024 + k0 + c4 * 4) = o;
    }
  } else {
    int idx = (bx - 5376) * 256 + tid;
    ushort4 o;
    if (idx < 16368) {
      float4 v = ((const float4*)de)[idx];
      o.x = f2bf(v.x); o.y = f2bf(v.y); o.z = f2bf(v.z); o.w = f2bf(v.w);
    } else { o.x = 0; o.y = 0; o.z = 0; o.w = 0; }
    ((ushort4*)E)[idx] = o;
  }
}

// ---------------- fused QKV GEMM (256x256, 8 waves, BK=64, swizzled staging) ----------------
// XCD-swizzled block mapping: 216 blocks = 8 XCDs x 27 (bijective chunked).
__global__ __launch_bounds__(512) void k_gemm(const unsigned short* __restrict__ X,
                                              const unsigned short* __restrict__ Wt,
                                              const float* __restrict__ bq,
                                              const float* __restrict__ bk,
                                              const float* __restrict__ bv,
                                              unsigned short* __restrict__ Q,
                                              unsigned short* __restrict__ K,
                                              unsigned short* __restrict__ Vt,
                                              unsigned short* __restrict__ IK,
                                              unsigned short* __restrict__ IVt) {
  __shared__ unsigned short smem[65536];   // A[2]@0 (2x32KB), B[2]@32768; epilogue reuses all
  const int tid = threadIdx.x, lane = tid & 63, w = tid >> 6;
  const int lg = lane >> 4, lc = lane & 15;
  const int bid = blockIdx.x + 12 * blockIdx.y;
  const int swz = (bid & 7) * 27 + (bid >> 3);          // 216 = 8*27
  const int m0 = (swz / 12) * 256, n0 = (swz % 12) * 256;
  const int wr = w >> 2, wc = w & 3;
  const int which = n0 >> 10;
  const int h0 = (n0 & 1023) >> 6;
  const float* barr = (which == 0) ? bq : (which == 1) ? bk : bv;

  f32x4 acc[8][4];
  #pragma unroll
  for (int i = 0; i < 8; ++i)
    #pragma unroll
    for (int j = 0; j < 4; ++j) acc[i][j] = (f32x4){0.f, 0.f, 0.f, 0.f};

  const unsigned short* ap[4];
  const unsigned short* bp[4];
  #pragma unroll
  for (int q = 0; q < 4; ++q) {
    const int c = (w * 4 + q) * 64 + lane;
    const int row = c >> 3, cc = c & 7;
    const int sc = (cc ^ (row & 7)) * 8;
    ap[q] = X  + (size_t)(m0 + row) * 1024 + sc;
    bp[q] = Wt + (size_t)(n0 + row) * 1024 + sc;
  }

  #define STAGE(bi)                                                        \
    {                                                                      \
      _Pragma("unroll")                                                    \
      for (int q_ = 0; q_ < 4; ++q_) {                                     \
        gload_lds16(ap[q_], smem + (bi) * 16384 + ((w * 4 + q_) * 64) * 8);\
        gload_lds16(bp[q_], smem + 32768 + (bi) * 16384 + ((w * 4 + q_) * 64) * 8); \
        ap[q_] += 64; bp[q_] += 64;                                        \
      }                                                                    \
    }

  STAGE(0);
  int cur = 0;
  for (int kt = 0; kt < 16; ++kt) {
    __syncthreads();
    if (kt + 1 < 16) STAGE(cur ^ 1);
    const unsigned short* A = smem + cur * 16384;
    const unsigned short* B = smem + 32768 + cur * 16384;
    #pragma unroll
    for (int kc = 0; kc < 2; ++kc) {
      bf16x8 af[8], bfr[4];
      #pragma unroll
      for (int i = 0; i < 8; ++i)
        af[i] = read_swz128(A, wr * 128 + i * 16 + lc, kc * 64 + lg * 16);
      #pragma unroll
      for (int j = 0; j < 4; ++j)
        bfr[j] = read_swz128(B, wc * 64 + j * 16 + lc, kc * 64 + lg * 16);
      __builtin_amdgcn_s_setprio(1);
      #pragma unroll
      for (int i = 0; i < 8; ++i)
        #pragma unroll
        for (int j = 0; j < 4; ++j)
          acc[i][j] = mfma16(af[i], bfr[j], acc[i][j]);
      __builtin_amdgcn_s_setprio(0);
    }
    cur ^= 1;
  }
  #undef STAGE

  __syncthreads();
  {
    char* Cs = (char*)smem;
    #pragma unroll
    for (int j = 0; j < 4; ++j) {
      const float bias = barr[(n0 & 1023) + wc * 64 + j * 16 + lc];
      #pragma unroll
      for (int i = 0; i < 8; ++i)
        #pragma unroll
        for (int ii = 0; ii < 4; ++ii) {
          int row = wr * 128 + i * 16 + lg * 4 + ii;
          int col = wc * 64 + j * 16 + lc;
          if (which == 2) { int t = row; row = col; col = t; }
          *(unsigned short*)(Cs + row * 512 + ((col * 2) ^ (((row >> 2) & 31) << 4))) =
              f2bf(acc[i][j][ii] + bias);
        }
    }
  }
  __syncthreads();
  {
    const char* Cs = (const char*)smem;
    const int row = tid >> 1;
    #pragma unroll
    for (int rnd = 0; rnd < 2; ++rnd) {
      const int q = (tid & 1) + rnd * 2;
      uint4 cvec[8];
      #pragma unroll
      for (int c8 = 0; c8 < 8; ++c8)
        cvec[c8] = *(const uint4*)(Cs + row * 512 +
                                   ((q * 128 + c8 * 16) ^ (((row >> 2) & 31) << 4)));
      unsigned short* dst = nullptr;
      if (which != 2) {
        const int gm = m0 + row, hh = h0 + q;
        if (gm < 4096) {
          const int bb = gm >> 9, ss = gm & 511;
          unsigned short* base = (which == 0) ? Q : K;
          dst = base + (((size_t)(bb * NH + hh) * 512 + ss) << 6);
        } else if (which == 1) {
          const int mi = gm - 4096, bb = mi >> 6, si = mi & 63;
          dst = IK + (((size_t)(bb * NH + hh) * 64 + si) << 6);
        }
      } else {
        const int dd = row, hh = h0 + (dd >> 6), ddl = dd & 63;
        const int gm0 = m0 + q * 64;
        if (gm0 < 4096) {
          const int bb = gm0 >> 9, ss0 = gm0 & 511;
          dst = Vt + ((size_t)(bb * NH + hh) * 64 + ddl) * 512 + ss0;
        } else {
          const int mi0 = gm0 - 4096, bb = mi0 >> 6;
          dst = IVt + (((size_t)(bb * NH + hh) * 64 + ddl) << 6);
        }
      }
      if (dst) {
        #pragma unroll
        for (int c8 = 0; c8 < 8; ++c8)
          *(uint4*)(dst + c8 * 8) = cvec[c8];
      }
    }
  }
}

// ---------------- bias tile kernel (v4: transposed tables, vectorized writes) ----------------
// Tables stored [128 u][64 row], physical col = row ^ ((u&7)<<3); the MFMA
// accumulator's 4 i-values (4 consecutive rows, same u) become ONE ushort4
// store.  LDS overlay unchanged: 32 KB -> 5 blocks/CU.
__global__ __launch_bounds__(256) void k_bias(const unsigned short* __restrict__ Qg,
                                              const unsigned short* __restrict__ Kg,
                                              const unsigned short* __restrict__ Eg,
                                              const float* __restrict__ mask,
                                              unsigned short* __restrict__ Bias) {
  const int rt = blockIdx.x, lt = blockIdx.y, bh = blockIdx.z;
  const int l0 = lt * 64, r0 = rt * 64;
  const int p0 = l0 - r0 + 448;
  const int tid = threadIdx.x, lane = tid & 63, w = tid >> 6;
  const int lg = lane >> 4, lc = lane & 15;
  const int ubase = w * 32;
  const int b = bh >> 4;

  __shared__ unsigned short smem[16384];     // 32 KB
  unsigned short* Qs  = smem;                // phase A: 8 KB
  unsigned short* Ks  = smem + 4096;         // phase A: 8 KB
  unsigned short* qdl = smem + 8192;         // 16 KB, [128][64] (persistent)
  unsigned short* kdl = smem;                // phase B: 16 KB over Qs+Ks

  stage_tile_swz(Qg + ((size_t)(bh * 512 + l0)) * 64, 64, Qs, w, lane);
  stage_tile_swz(Kg + ((size_t)(bh * 512 + r0)) * 64, 64, Ks, w, lane);

  bf16x8 eb[2][2];
  #pragma unroll
  for (int ns = 0; ns < 2; ++ns) {
    const int u = ubase + ns * 16 + lc;
    const unsigned short* ep = Eg + (size_t)(p0 + u) * 64 + lg * 8;
    eb[ns][0] = *(const bf16x8*)(ep);
    eb[ns][1] = *(const bf16x8*)(ep + 32);
  }
  __syncthreads();    // staging complete

  f32x4 da[4][2];
  // qd: MFMAs over Qs -> qdl (disjoint region)
  #pragma unroll
  for (int ms = 0; ms < 4; ++ms) { da[ms][0] = (f32x4){0,0,0,0}; da[ms][1] = (f32x4){0,0,0,0}; }
  #pragma unroll
  for (int kc = 0; kc < 2; ++kc)
    #pragma unroll
    for (int ms = 0; ms < 4; ++ms) {
      bf16x8 a = read_swz(Qs, ms * 16 + lc, kc * 64 + lg * 16);
      da[ms][0] = mfma16(a, eb[0][kc], da[ms][0]);
      da[ms][1] = mfma16(a, eb[1][kc], da[ms][1]);
    }
  #pragma unroll
  for (int ns = 0; ns < 2; ++ns) {
    const int u = ubase + ns * 16 + lc;
    const int k = (u & 7) << 3;
    #pragma unroll
    for (int ms = 0; ms < 4; ++ms) {
      ushort4 o;
      o.x = f2bf(da[ms][ns][0]); o.y = f2bf(da[ms][ns][1]);
      o.z = f2bf(da[ms][ns][2]); o.w = f2bf(da[ms][ns][3]);
      *(ushort4*)(qdl + u * 64 + ((ms * 16 + lg * 4) ^ k)) = o;
    }
  }
  // kd: MFMAs over Ks, held in regs across the barrier
  #pragma unroll
  for (int ms = 0; ms < 4; ++ms) { da[ms][0] = (f32x4){0,0,0,0}; da[ms][1] = (f32x4){0,0,0,0}; }
  #pragma unroll
  for (int kc = 0; kc < 2; ++kc)
    #pragma unroll
    for (int ms = 0; ms < 4; ++ms) {
      bf16x8 a = read_swz(Ks, ms * 16 + lc, kc * 64 + lg * 16);
      da[ms][0] = mfma16(a, eb[0][kc], da[ms][0]);
      da[ms][1] = mfma16(a, eb[1][kc], da[ms][1]);
    }
  __syncthreads();    // Qs/Ks reads done; safe to overwrite with kdl
  #pragma unroll
  for (int ns = 0; ns < 2; ++ns) {
    const int u = ubase + ns * 16 + lc;
    const int k = (u & 7) << 3;
    #pragma unroll
    for (int ms = 0; ms < 4; ++ms) {
      ushort4 o;
      o.x = f2bf(da[ms][ns][0]); o.y = f2bf(da[ms][ns][1]);
      o.z = f2bf(da[ms][ns][2]); o.w = f2bf(da[ms][ns][3]);
      *(ushort4*)(kdl + u * 64 + ((ms * 16 + lg * 4) ^ k)) = o;
    }
  }
  __syncthreads();    // tables visible

  {
    unsigned short* dst = Bias + (((size_t)(bh * 64 + lt * 8 + rt)) << 12);
    #pragma unroll
    for (int ns = 0; ns < 4; ++ns) {
      const int ri = ns * 16 + lc;
      const float mk2 = mask[b * SEQ + r0 + ri] * L2E;
      ushort4 o;
      #pragma unroll
      for (int i = 0; i < 4; ++i) {
        const int li = w * 16 + lg * 4 + i;
        const int uq = li - ri + 63;
        const int k = (uq & 7) << 3;
        const float qv = bf2f(qdl[uq * 64 + (li ^ k)]);
        const float kv = bf2f(kdl[uq * 64 + (ri ^ k)]);
        const unsigned short val = f2bf((qv + kv) * C2 + mk2);
        if (i == 0) o.x = val; else if (i == 1) o.y = val;
        else if (i == 2) o.z = val; else o.w = val;
      }
      *(ushort4*)(dst + (w * 4 + ns) * 256 + lane * 4) = o;
    }
  }
}

// ---------------- fused attention ----------------
// flash, dbuf K/V, reg bias, exp2 softmax, lazy-max defer, ones-MFMA denominators.
__global__ __launch_bounds__(256) void k_attn(const unsigned short* __restrict__ Qg,
                                              const unsigned short* __restrict__ Kg,
                                              const unsigned short* __restrict__ Vtg,
                                              const unsigned short* __restrict__ IKg,
                                              const unsigned short* __restrict__ IVtg,
                                              const unsigned short* __restrict__ Bias,
                                              const float* __restrict__ imask,
                                              const float* __restrict__ gate,
                                              float* __restrict__ out) {
  const int lt = blockIdx.x, h = blockIdx.y, b = blockIdx.z;
  const int l0 = lt * 64;
  const int tid = threadIdx.x;
  const int lane = tid & 63, w = tid >> 6;
  const int lg = lane >> 4, lc = lane & 15;
  const int bh = b * NH + h;
  const short ob = (short)0x3F80;
  const bf16x8 ONES = {ob, ob, ob, ob, ob, ob, ob, ob};

  __shared__ unsigned short Ks[2 * 64 * 64];
  __shared__ unsigned short Vts[2 * 64 * 64];
  __shared__ unsigned short Ps[64 * 64];

  bf16x8 qa[2];
  {
    const unsigned short* qrow = Qg + ((size_t)(bh * 512 + l0 + w * 16 + lc)) * 64;
    qa[0] = *(const bf16x8*)(qrow + lg * 8);
    qa[1] = *(const bf16x8*)(qrow + 32 + lg * 8);
  }

  f32x4 oacc[4];
  #pragma unroll
  for (int i = 0; i < 4; ++i) oacc[i] = (f32x4){0.f, 0.f, 0.f, 0.f};
  float mrun[4], lrun[4];
  #pragma unroll
  for (int i = 0; i < 4; ++i) { mrun[i] = -3.0e38f; lrun[i] = 0.f; }

  stage_tile_swz(Kg + ((size_t)(bh * 512)) * 64, 64, Ks, w, lane);
  stage_tile_swz(Vtg + (size_t)bh * 64 * 512, 512, Vts, w, lane);
  const unsigned short* btbase = Bias + (((size_t)(bh * 64 + lt * 8)) << 12);
  bf16x4 brow[4];
  #pragma unroll
  for (int ns = 0; ns < 4; ++ns)
    brow[ns] = *(const bf16x4*)(btbase + (w * 4 + ns) * 256 + lane * 4);

  for (int rt = 0; rt < 8; ++rt) {
    const int r0 = rt * 64;
    const int cur = rt & 1;
    __syncthreads();

    if (rt < 7) {
      stage_tile_swz(Kg + ((size_t)(bh * 512 + r0 + 64)) * 64, 64, Ks + (cur ^ 1) * 4096, w, lane);
      stage_tile_swz(Vtg + (size_t)bh * 64 * 512 + r0 + 64, 512, Vts + (cur ^ 1) * 4096, w, lane);
    } else {
      stage_tile_swz(IKg + (size_t)bh * 4096, 64, Ks, w, lane);
      stage_tile_swz(IVtg + (size_t)bh * 4096, 64, Vts, w, lane);
    }
    bf16x4 bnext[4];
    if (rt < 7) {
      const unsigned short* bt = btbase + ((size_t)(rt + 1) << 12);
      #pragma unroll
      for (int ns = 0; ns < 4; ++ns)
        bnext[ns] = *(const bf16x4*)(bt + (w * 4 + ns) * 256 + lane * 4);
    }

    const unsigned short* Kc = Ks + cur * 4096;
    const unsigned short* Vc = Vts + cur * 4096;

    f32x4 sacc[4];
    #pragma unroll
    for (int ns = 0; ns < 4; ++ns) sacc[ns] = (f32x4){0.f, 0.f, 0.f, 0.f};
    __builtin_amdgcn_s_setprio(1);
    #pragma unroll
    for (int kc = 0; kc < 2; ++kc)
      #pragma unroll
      for (int ns = 0; ns < 4; ++ns) {
        bf16x8 kb = read_swz(Kc, ns * 16 + lc, kc * 64 + lg * 16);
        sacc[ns] = mfma16(qa[kc], kb, sacc[ns]);
      }
    __builtin_amdgcn_s_setprio(0);
    float sv[4][4];
    #pragma unroll
    for (int ns = 0; ns < 4; ++ns)
      #pragma unroll
      for (int i = 0; i < 4; ++i)
        sv[ns][i] = fmaf(sacc[ns][i], C2, bf2f((unsigned short)brow[ns][i]));

    float mt[4];
    #pragma unroll
    for (int i = 0; i < 4; ++i)
      mt[i] = fmaxf(fmaxf(sv[0][i], sv[1][i]), fmaxf(sv[2][i], sv[3][i]));
    bool need = false;
    #pragma unroll
    for (int i = 0; i < 4; ++i) need = need || (mt[i] > mrun[i] + DEFER_THR);
    if (__any(need)) {
      #pragma unroll
      for (int i = 0; i < 4; ++i) {
        float m_ = mt[i];
        #pragma unroll
        for (int m = 1; m <= 8; m <<= 1) m_ = fmaxf(m_, __shfl_xor(m_, m));
        const float mnew = fmaxf(mrun[i], m_);
        const float fr = exp2f(mrun[i] - mnew);
        mrun[i] = mnew;
        lrun[i] *= fr;
        #pragma unroll
        for (int ds = 0; ds < 4; ++ds) oacc[ds][i] *= fr;
      }
    }
    #pragma unroll
    for (int ns = 0; ns < 4; ++ns)
      #pragma unroll
      for (int i = 0; i < 4; ++i)
        sv[ns][i] = exp2f(sv[ns][i] - mrun[i]);
    #pragma unroll
    for (int ns = 0; ns < 4; ++ns)
      #pragma unroll
      for (int i = 0; i < 4; ++i) {
        const int row = w * 16 + lg * 4 + i;
        const int cb = (ns * 16 + lc) * 2;
        *(unsigned short*)((char*)Ps + row * 128 + (cb ^ ((row & 7) << 4))) = f2bf(sv[ns][i]);
      }
    f32x4 lsum = (f32x4){0.f, 0.f, 0.f, 0.f};
    __builtin_amdgcn_s_setprio(1);
    #pragma unroll
    for (int kc = 0; kc < 2; ++kc) {
      bf16x8 pa = read_swz(Ps, w * 16 + lc, kc * 64 + lg * 16);
      lsum = mfma16(pa, ONES, lsum);
      #pragma unroll
      for (int ds = 0; ds < 4; ++ds) {
        bf16x8 vb = read_swz(Vc, ds * 16 + lc, kc * 64 + lg * 16);
        oacc[ds] = mfma16(pa, vb, oacc[ds]);
      }
    }
    __builtin_amdgcn_s_setprio(0);
    #pragma unroll
    for (int i = 0; i < 4; ++i) lrun[i] += lsum[i];
    if (rt < 7) {
      #pragma unroll
      for (int ns = 0; ns < 4; ++ns) brow[ns] = bnext[ns];
    }
  }

  // ---- instruct branch ----
  {
    __syncthreads();
    f32x4 sacc[4];
    #pragma unroll
    for (int ns = 0; ns < 4; ++ns) sacc[ns] = (f32x4){0.f, 0.f, 0.f, 0.f};
    #pragma unroll
    for (int kc = 0; kc < 2; ++kc)
      #pragma unroll
      for (int ns = 0; ns < 4; ++ns) {
        bf16x8 kb = read_swz(Ks, ns * 16 + lc, kc * 64 + lg * 16);
        sacc[ns] = mfma16(qa[kc], kb, sacc[ns]);
      }
    float sv[4][4];
    #pragma unroll
    for (int ns = 0; ns < 4; ++ns) {
      const float mk2 = imask[b * SIN + ns * 16 + lc] * L2E;
      #pragma unroll
      for (int i = 0; i < 4; ++i) sv[ns][i] = fmaf(sacc[ns][i], C2, mk2);
    }
    #pragma unroll
    for (int i = 0; i < 4; ++i) {
      float mt = fmaxf(fmaxf(sv[0][i], sv[1][i]), fmaxf(sv[2][i], sv[3][i]));
      #pragma unroll
      for (int m = 1; m <= 8; m <<= 1) mt = fmaxf(mt, __shfl_xor(mt, m));
      #pragma unroll
      for (int ns = 0; ns < 4; ++ns) sv[ns][i] = exp2f(sv[ns][i] - mt);
    }
    #pragma unroll
    for (int ns = 0; ns < 4; ++ns)
      #pragma unroll
      for (int i = 0; i < 4; ++i) {
        const int row = w * 16 + lg * 4 + i;
        const int cb = (ns * 16 + lc) * 2;
        *(unsigned short*)((char*)Ps + row * 128 + (cb ^ ((row & 7) << 4))) = f2bf(sv[ns][i]);
      }
    f32x4 iacc[4];
    #pragma unroll
    for (int ds = 0; ds < 4; ++ds) iacc[ds] = (f32x4){0.f, 0.f, 0.f, 0.f};
    f32x4 isum = (f32x4){0.f, 0.f, 0.f, 0.f};
    #pragma unroll
    for (int kc = 0; kc < 2; ++kc) {
      bf16x8 pa = read_swz(Ps, w * 16 + lc, kc * 64 + lg * 16);
      isum = mfma16(pa, ONES, isum);
      #pragma unroll
      for (int ds = 0; ds < 4; ++ds) {
        bf16x8 vb = read_swz(Vts, ds * 16 + lc, kc * 64 + lg * 16);
        iacc[ds] = mfma16(pa, vb, iacc[ds]);
      }
    }
    const float tg = tanhf(gate[h]);
    #pragma unroll
    for (int ds = 0; ds < 4; ++ds)
      #pragma unroll
      for (int i = 0; i < 4; ++i) {
        const int li = w * 16 + lg * 4 + i;
        const float val = oacc[ds][i] / lrun[i] + tg * (iacc[ds][i] / isum[i]);
        out[(size_t)(b * SEQ + l0 + li) * 1024 + h * 64 + ds * 16 + lc] = val;
      }
  }
}

// ---------------- launch ----------------

extern "C" void kernel_launch(void* const* d_in, const int* in_sizes, int n_in,
                              void* d_out, int out_size, void* d_ws, size_t ws_size,
                              hipStream_t stream) {
  (void)in_sizes; (void)n_in; (void)out_size; (void)ws_size;
  const float* hs    = (const float*)d_in[0];
  const float* ihs   = (const float*)d_in[1];
  const float* mask  = (const float*)d_in[2];
  const float* imask = (const float*)d_in[3];
  const float* Wq    = (const float*)d_in[4];
  const float* bq    = (const float*)d_in[5];
  const float* Wk    = (const float*)d_in[6];
  const float* bk    = (const float*)d_in[7];
  const float* Wv    = (const float*)d_in[8];
  const float* bv    = (const float*)d_in[9];
  const float* de    = (const float*)d_in[10];
  const float* gate  = (const float*)d_in[11];
  float* out = (float*)d_out;

  char* ws = (char*)d_ws;
  size_t off = 0;
  auto alloc = [&](size_t bytes) -> void* {
    void* p = ws + off;
    off += (bytes + 255) & ~(size_t)255;
    return p;
  };
  unsigned short* X    = (unsigned short*)alloc((size_t)4608 * 1024 * 2);
  unsigned short* Wt   = (unsigned short*)alloc((size_t)3072 * 1024 * 2);
  unsigned short* E    = (unsigned short*)alloc((size_t)1024 * 64 * 2);
  unsigned short* Qb   = (unsigned short*)alloc((size_t)8 * 16 * 512 * 64 * 2);
  unsigned short* Kb   = (unsigned short*)alloc((size_t)8 * 16 * 512 * 64 * 2);
  unsigned short* Vtb  = (unsigned short*)alloc((size_t)8 * 16 * 64 * 512 * 2);
  unsigned short* IKb  = (unsigned short*)alloc((size_t)8 * 16 * 64 * 64 * 2);
  unsigned short* IVtb = (unsigned short*)alloc((size_t)8 * 16 * 64 * 64 * 2);
  unsigned short* Bias = (unsigned short*)alloc((size_t)128 * 64 * 4096 * 2);  // 64 MiB

  k_convert_all<<<5440, 256, 0, stream>>>(hs, ihs, de, Wq, Wk, Wv, X, E, Wt);
  k_gemm<<<dim3(12, 18), 512, 0, stream>>>(X, Wt, bq, bk, bv, Qb, Kb, Vtb, IKb, IVtb);
  k_bias<<<dim3(8, 8, 128), 256, 0, stream>>>(Qb, Kb, E, mask, Bias);
  k_attn<<<dim3(8, 16, 8), 256, 0, stream>>>(Qb, Kb, Vtb, IKb, IVtb, Bias, imask, gate, out);
}

// Round 23
// 129.684 us; speedup vs baseline: 1.0552x; 1.0400x over previous
//
#include <hip/hip_runtime.h>

#define NH 16
#define DH 64
#define SEQ 512
#define SIN 64
#define NBATCH 8

#define L2E 1.4426950408889634f          // log2(e)
#define C2  0.18033688011112043f         // 0.125 * log2(e)
#define DEFER_THR 11.5412435f            // 8 * log2(e)

typedef short bf16x8 __attribute__((ext_vector_type(8)));
typedef short bf16x4 __attribute__((ext_vector_type(4)));
typedef float f32x4 __attribute__((ext_vector_type(4)));

__device__ __forceinline__ unsigned short f2bf(float f) {
  union { float f; unsigned u; } v; v.f = f;
  unsigned r = v.u + 0x7FFFu + ((v.u >> 16) & 1u);
  return (unsigned short)(r >> 16);
}
__device__ __forceinline__ float bf2f(unsigned short b) {
  union { unsigned u; float f; } v; v.u = ((unsigned)b) << 16;
  return v.f;
}
__device__ __forceinline__ f32x4 mfma16(bf16x8 a, bf16x8 b, f32x4 c) {
  return __builtin_amdgcn_mfma_f32_16x16x32_bf16(a, b, c, 0, 0, 0);
}
__device__ __forceinline__ void gload_lds16(const unsigned short* g, unsigned short* l) {
  __builtin_amdgcn_global_load_lds((const __attribute__((address_space(1))) void*)g,
                                   (__attribute__((address_space(3))) void*)l, 16, 0, 0);
}

// 64x64 bf16 tile in LDS, logical [64][64], physical byte swizzle
// phys = row*128 + (colbyte ^ ((row&7)<<4)); staged with pre-swizzled global src.
__device__ __forceinline__ void stage_tile_swz(const unsigned short* g, int gstride,
                                               unsigned short* lds, int w, int lane) {
  #pragma unroll
  for (int c = 0; c < 2; ++c) {
    const int row = w * 16 + c * 8 + (lane >> 3);
    const int cb = ((lane & 7) ^ (lane >> 3)) << 4;
    gload_lds16(g + (size_t)row * gstride + (cb >> 1),
                lds + (w * 16 + c * 8) * 64);
  }
}
__device__ __forceinline__ bf16x8 read_swz(const unsigned short* lds, int row, int colbyte) {
  return *(const bf16x8*)((const char*)(lds + row * 64) + (colbyte ^ ((row & 7) << 4)));
}
// same swizzle for 128-byte rows (BK=64 staging in k_gemm)
__device__ __forceinline__ bf16x8 read_swz128(const unsigned short* lds, int row, int colbyte) {
  return *(const bf16x8*)((const char*)lds + row * 128 + (colbyte ^ ((row & 7) << 4)));
}

// ---------------- merged convert kernel ----------------
__global__ __launch_bounds__(256) void k_convert_all(const float* __restrict__ hs,
                                                     const float* __restrict__ ihs,
                                                     const float* __restrict__ de,
                                                     const float* __restrict__ Wq,
                                                     const float* __restrict__ Wk,
                                                     const float* __restrict__ Wv,
                                                     unsigned short* __restrict__ X,
                                                     unsigned short* __restrict__ E,
                                                     unsigned short* __restrict__ Wt) {
  __shared__ float t[64][65];
  const int bx = blockIdx.x, tid = threadIdx.x;
  if (bx < 4608) {
    int idx = bx * 256 + tid;
    float4 v;
    if (idx < 1048576) v = ((const float4*)hs)[idx];
    else               v = ((const float4*)ihs)[idx - 1048576];
    ushort4 o; o.x = f2bf(v.x); o.y = f2bf(v.y); o.z = f2bf(v.z); o.w = f2bf(v.w);
    ((ushort4*)X)[idx] = o;
  } else if (bx < 5376) {
    const int wb = bx - 4608;
    const int z = wb >> 8, rem = wb & 255;
    const float* W = (z == 0) ? Wq : (z == 1) ? Wk : Wv;
    const int n0 = (rem & 15) * 64, k0 = (rem >> 4) * 64;
    #pragma unroll
    for (int q = 0; q < 4; ++q) {
      int s = q * 256 + tid;
      int r = s >> 4, c4 = s & 15;
      float4 v = *(const float4*)(W + (size_t)(k0 + r) * 1024 + n0 + c4 * 4);
      t[r][c4 * 4 + 0] = v.x; t[r][c4 * 4 + 1] = v.y;
      t[r][c4 * 4 + 2] = v.z; t[r][c4 * 4 + 3] = v.w;
    }
    __syncthreads();
    #pragma unroll
    for (int q = 0; q < 4; ++q) {
      int s = q * 256 + tid;
      int rn = s >> 4, c4 = s & 15;
      ushort4 o;
      o.x = f2bf(t[c4 * 4 + 0][rn]); o.y = f2bf(t[c4 * 4 + 1][rn]);
      o.z = f2bf(t[c4 * 4 + 2][rn]); o.w = f2bf(t[c4 * 4 + 3][rn]);
      *(ushort4*)(Wt + ((size_t)(z << 10) + n0 + rn) * 1024 + k0 + c4 * 4) = o;
    }
  } else {
    int idx = (bx - 5376) * 256 + tid;
    ushort4 o;
    if (idx < 16368) {
      float4 v = ((const float4*)de)[idx];
      o.x = f2bf(v.x); o.y = f2bf(v.y); o.z = f2bf(v.z); o.w = f2bf(v.w);
    } else { o.x = 0; o.y = 0; o.z = 0; o.w = 0; }
    ((ushort4*)E)[idx] = o;
  }
}

// ---------------- fused QKV GEMM (256x256, 8 waves, BK=64, swizzled staging) ----------------
// XCD-swizzled block mapping: 216 blocks = 8 XCDs x 27 (bijective chunked).
__global__ __launch_bounds__(512) void k_gemm(const unsigned short* __restrict__ X,
                                              const unsigned short* __restrict__ Wt,
                                              const float* __restrict__ bq,
                                              const float* __restrict__ bk,
                                              const float* __restrict__ bv,
                                              unsigned short* __restrict__ Q,
                                              unsigned short* __restrict__ K,
                                              unsigned short* __restrict__ Vt,
                                              unsigned short* __restrict__ IK,
                                              unsigned short* __restrict__ IVt) {
  __shared__ unsigned short smem[65536];   // A[2]@0 (2x32KB), B[2]@32768; epilogue reuses all
  const int tid = threadIdx.x, lane = tid & 63, w = tid >> 6;
  const int lg = lane >> 4, lc = lane & 15;
  const int bid = blockIdx.x + 12 * blockIdx.y;
  const int swz = (bid & 7) * 27 + (bid >> 3);          // 216 = 8*27
  const int m0 = (swz / 12) * 256, n0 = (swz % 12) * 256;
  const int wr = w >> 2, wc = w & 3;
  const int which = n0 >> 10;
  const int h0 = (n0 & 1023) >> 6;
  const float* barr = (which == 0) ? bq : (which == 1) ? bk : bv;

  f32x4 acc[8][4];
  #pragma unroll
  for (int i = 0; i < 8; ++i)
    #pragma unroll
    for (int j = 0; j < 4; ++j) acc[i][j] = (f32x4){0.f, 0.f, 0.f, 0.f};

  const unsigned short* ap[4];
  const unsigned short* bp[4];
  #pragma unroll
  for (int q = 0; q < 4; ++q) {
    const int c = (w * 4 + q) * 64 + lane;
    const int row = c >> 3, cc = c & 7;
    const int sc = (cc ^ (row & 7)) * 8;
    ap[q] = X  + (size_t)(m0 + row) * 1024 + sc;
    bp[q] = Wt + (size_t)(n0 + row) * 1024 + sc;
  }

  #define STAGE(bi)                                                        \
    {                                                                      \
      _Pragma("unroll")                                                    \
      for (int q_ = 0; q_ < 4; ++q_) {                                     \
        gload_lds16(ap[q_], smem + (bi) * 16384 + ((w * 4 + q_) * 64) * 8);\
        gload_lds16(bp[q_], smem + 32768 + (bi) * 16384 + ((w * 4 + q_) * 64) * 8); \
        ap[q_] += 64; bp[q_] += 64;                                        \
      }                                                                    \
    }

  STAGE(0);
  int cur = 0;
  for (int kt = 0; kt < 16; ++kt) {
    __syncthreads();
    if (kt + 1 < 16) STAGE(cur ^ 1);
    const unsigned short* A = smem + cur * 16384;
    const unsigned short* B = smem + 32768 + cur * 16384;
    #pragma unroll
    for (int kc = 0; kc < 2; ++kc) {
      bf16x8 af[8], bfr[4];
      #pragma unroll
      for (int i = 0; i < 8; ++i)
        af[i] = read_swz128(A, wr * 128 + i * 16 + lc, kc * 64 + lg * 16);
      #pragma unroll
      for (int j = 0; j < 4; ++j)
        bfr[j] = read_swz128(B, wc * 64 + j * 16 + lc, kc * 64 + lg * 16);
      __builtin_amdgcn_s_setprio(1);
      #pragma unroll
      for (int i = 0; i < 8; ++i)
        #pragma unroll
        for (int j = 0; j < 4; ++j)
          acc[i][j] = mfma16(af[i], bfr[j], acc[i][j]);
      __builtin_amdgcn_s_setprio(0);
    }
    cur ^= 1;
  }
  #undef STAGE

  __syncthreads();
  {
    char* Cs = (char*)smem;
    #pragma unroll
    for (int j = 0; j < 4; ++j) {
      const float bias = barr[(n0 & 1023) + wc * 64 + j * 16 + lc];
      #pragma unroll
      for (int i = 0; i < 8; ++i)
        #pragma unroll
        for (int ii = 0; ii < 4; ++ii) {
          int row = wr * 128 + i * 16 + lg * 4 + ii;
          int col = wc * 64 + j * 16 + lc;
          if (which == 2) { int t = row; row = col; col = t; }
          *(unsigned short*)(Cs + row * 512 + ((col * 2) ^ (((row >> 2) & 31) << 4))) =
              f2bf(acc[i][j][ii] + bias);
        }
    }
  }
  __syncthreads();
  {
    const char* Cs = (const char*)smem;
    const int row = tid >> 1;
    #pragma unroll
    for (int rnd = 0; rnd < 2; ++rnd) {
      const int q = (tid & 1) + rnd * 2;
      uint4 cvec[8];
      #pragma unroll
      for (int c8 = 0; c8 < 8; ++c8)
        cvec[c8] = *(const uint4*)(Cs + row * 512 +
                                   ((q * 128 + c8 * 16) ^ (((row >> 2) & 31) << 4)));
      unsigned short* dst = nullptr;
      if (which != 2) {
        const int gm = m0 + row, hh = h0 + q;
        if (gm < 4096) {
          const int bb = gm >> 9, ss = gm & 511;
          unsigned short* base = (which == 0) ? Q : K;
          dst = base + (((size_t)(bb * NH + hh) * 512 + ss) << 6);
        } else if (which == 1) {
          const int mi = gm - 4096, bb = mi >> 6, si = mi & 63;
          dst = IK + (((size_t)(bb * NH + hh) * 64 + si) << 6);
        }
      } else {
        const int dd = row, hh = h0 + (dd >> 6), ddl = dd & 63;
        const int gm0 = m0 + q * 64;
        if (gm0 < 4096) {
          const int bb = gm0 >> 9, ss0 = gm0 & 511;
          dst = Vt + ((size_t)(bb * NH + hh) * 64 + ddl) * 512 + ss0;
        } else {
          const int mi0 = gm0 - 4096, bb = mi0 >> 6;
          dst = IVt + (((size_t)(bb * NH + hh) * 64 + ddl) << 6);
        }
      }
      if (dst) {
        #pragma unroll
        for (int c8 = 0; c8 < 8; ++c8)
          *(uint4*)(dst + c8 * 8) = cvec[c8];
      }
    }
  }
}

// ---------------- bias tile kernel (v4: transposed tables, vectorized writes) ----------------
// Tables stored [128 u][64 row], physical col = row ^ ((u&7)<<3); the MFMA
// accumulator's 4 i-values (4 consecutive rows, same u) become ONE ushort4
// store.  LDS overlay unchanged: 32 KB -> 5 blocks/CU.
__global__ __launch_bounds__(256) void k_bias(const unsigned short* __restrict__ Qg,
                                              const unsigned short* __restrict__ Kg,
                                              const unsigned short* __restrict__ Eg,
                                              const float* __restrict__ mask,
                                              unsigned short* __restrict__ Bias) {
  const int rt = blockIdx.x, lt = blockIdx.y, bh = blockIdx.z;
  const int l0 = lt * 64, r0 = rt * 64;
  const int p0 = l0 - r0 + 448;
  const int tid = threadIdx.x, lane = tid & 63, w = tid >> 6;
  const int lg = lane >> 4, lc = lane & 15;
  const int ubase = w * 32;
  const int b = bh >> 4;

  __shared__ unsigned short smem[16384];     // 32 KB
  unsigned short* Qs  = smem;                // phase A: 8 KB
  unsigned short* Ks  = smem + 4096;         // phase A: 8 KB
  unsigned short* qdl = smem + 8192;         // 16 KB, [128][64] (persistent)
  unsigned short* kdl = smem;                // phase B: 16 KB over Qs+Ks

  stage_tile_swz(Qg + ((size_t)(bh * 512 + l0)) * 64, 64, Qs, w, lane);
  stage_tile_swz(Kg + ((size_t)(bh * 512 + r0)) * 64, 64, Ks, w, lane);

  bf16x8 eb[2][2];
  #pragma unroll
  for (int ns = 0; ns < 2; ++ns) {
    const int u = ubase + ns * 16 + lc;
    const unsigned short* ep = Eg + (size_t)(p0 + u) * 64 + lg * 8;
    eb[ns][0] = *(const bf16x8*)(ep);
    eb[ns][1] = *(const bf16x8*)(ep + 32);
  }
  __syncthreads();    // staging complete

  f32x4 da[4][2];
  // qd: MFMAs over Qs -> qdl (disjoint region)
  #pragma unroll
  for (int ms = 0; ms < 4; ++ms) { da[ms][0] = (f32x4){0,0,0,0}; da[ms][1] = (f32x4){0,0,0,0}; }
  #pragma unroll
  for (int kc = 0; kc < 2; ++kc)
    #pragma unroll
    for (int ms = 0; ms < 4; ++ms) {
      bf16x8 a = read_swz(Qs, ms * 16 + lc, kc * 64 + lg * 16);
      da[ms][0] = mfma16(a, eb[0][kc], da[ms][0]);
      da[ms][1] = mfma16(a, eb[1][kc], da[ms][1]);
    }
  #pragma unroll
  for (int ns = 0; ns < 2; ++ns) {
    const int u = ubase + ns * 16 + lc;
    const int k = (u & 7) << 3;
    #pragma unroll
    for (int ms = 0; ms < 4; ++ms) {
      ushort4 o;
      o.x = f2bf(da[ms][ns][0]); o.y = f2bf(da[ms][ns][1]);
      o.z = f2bf(da[ms][ns][2]); o.w = f2bf(da[ms][ns][3]);
      *(ushort4*)(qdl + u * 64 + ((ms * 16 + lg * 4) ^ k)) = o;
    }
  }
  // kd: MFMAs over Ks, held in regs across the barrier
  #pragma unroll
  for (int ms = 0; ms < 4; ++ms) { da[ms][0] = (f32x4){0,0,0,0}; da[ms][1] = (f32x4){0,0,0,0}; }
  #pragma unroll
  for (int kc = 0; kc < 2; ++kc)
    #pragma unroll
    for (int ms = 0; ms < 4; ++ms) {
      bf16x8 a = read_swz(Ks, ms * 16 + lc, kc * 64 + lg * 16);
      da[ms][0] = mfma16(a, eb[0][kc], da[ms][0]);
      da[ms][1] = mfma16(a, eb[1][kc], da[ms][1]);
    }
  __syncthreads();    // Qs/Ks reads done; safe to overwrite with kdl
  #pragma unroll
  for (int ns = 0; ns < 2; ++ns) {
    const int u = ubase + ns * 16 + lc;
    const int k = (u & 7) << 3;
    #pragma unroll
    for (int ms = 0; ms < 4; ++ms) {
      ushort4 o;
      o.x = f2bf(da[ms][ns][0]); o.y = f2bf(da[ms][ns][1]);
      o.z = f2bf(da[ms][ns][2]); o.w = f2bf(da[ms][ns][3]);
      *(ushort4*)(kdl + u * 64 + ((ms * 16 + lg * 4) ^ k)) = o;
    }
  }
  __syncthreads();    // tables visible

  {
    unsigned short* dst = Bias + (((size_t)(bh * 64 + lt * 8 + rt)) << 12);
    #pragma unroll
    for (int ns = 0; ns < 4; ++ns) {
      const int ri = ns * 16 + lc;
      const float mk2 = mask[b * SEQ + r0 + ri] * L2E;
      ushort4 o;
      #pragma unroll
      for (int i = 0; i < 4; ++i) {
        const int li = w * 16 + lg * 4 + i;
        const int uq = li - ri + 63;
        const int k = (uq & 7) << 3;
        const float qv = bf2f(qdl[uq * 64 + (li ^ k)]);
        const float kv = bf2f(kdl[uq * 64 + (ri ^ k)]);
        const unsigned short val = f2bf((qv + kv) * C2 + mk2);
        if (i == 0) o.x = val; else if (i == 1) o.y = val;
        else if (i == 2) o.z = val; else o.w = val;
      }
      *(ushort4*)(dst + (w * 4 + ns) * 256 + lane * 4) = o;
    }
  }
}

// ---------------- fused attention ----------------
// flash, dbuf K/V, reg bias, exp2 softmax, lazy-max defer, ones-MFMA denominators.
// XCD-grouped block decode: the 8 lt-tiles of one (b,h) share an XCD so its
// K/V stays L2-resident (16 groups x 160 KB = 2.6 MB < 4 MB per-XCD L2).
__global__ __launch_bounds__(256) void k_attn(const unsigned short* __restrict__ Qg,
                                              const unsigned short* __restrict__ Kg,
                                              const unsigned short* __restrict__ Vtg,
                                              const unsigned short* __restrict__ IKg,
                                              const unsigned short* __restrict__ IVtg,
                                              const unsigned short* __restrict__ Bias,
                                              const float* __restrict__ imask,
                                              const float* __restrict__ gate,
                                              float* __restrict__ out) {
  const int fb = blockIdx.x + 8 * (blockIdx.y + 16 * blockIdx.z);  // [0,1024)
  const int xcd = fb & 7, slot = fb >> 3;
  const int gidx = xcd + 8 * (slot >> 3);   // (b,h) group on XCD gidx%8
  const int lt = slot & 7;
  const int h = gidx & 15, b = gidx >> 4;
  const int l0 = lt * 64;
  const int tid = threadIdx.x;
  const int lane = tid & 63, w = tid >> 6;
  const int lg = lane >> 4, lc = lane & 15;
  const int bh = b * NH + h;
  const short ob = (short)0x3F80;
  const bf16x8 ONES = {ob, ob, ob, ob, ob, ob, ob, ob};

  __shared__ unsigned short Ks[2 * 64 * 64];
  __shared__ unsigned short Vts[2 * 64 * 64];
  __shared__ unsigned short Ps[64 * 64];

  bf16x8 qa[2];
  {
    const unsigned short* qrow = Qg + ((size_t)(bh * 512 + l0 + w * 16 + lc)) * 64;
    qa[0] = *(const bf16x8*)(qrow + lg * 8);
    qa[1] = *(const bf16x8*)(qrow + 32 + lg * 8);
  }

  f32x4 oacc[4];
  #pragma unroll
  for (int i = 0; i < 4; ++i) oacc[i] = (f32x4){0.f, 0.f, 0.f, 0.f};
  float mrun[4], lrun[4];
  #pragma unroll
  for (int i = 0; i < 4; ++i) { mrun[i] = -3.0e38f; lrun[i] = 0.f; }

  stage_tile_swz(Kg + ((size_t)(bh * 512)) * 64, 64, Ks, w, lane);
  stage_tile_swz(Vtg + (size_t)bh * 64 * 512, 512, Vts, w, lane);
  const unsigned short* btbase = Bias + (((size_t)(bh * 64 + lt * 8)) << 12);
  bf16x4 brow[4];
  #pragma unroll
  for (int ns = 0; ns < 4; ++ns)
    brow[ns] = *(const bf16x4*)(btbase + (w * 4 + ns) * 256 + lane * 4);

  for (int rt = 0; rt < 8; ++rt) {
    const int r0 = rt * 64;
    const int cur = rt & 1;
    __syncthreads();

    if (rt < 7) {
      stage_tile_swz(Kg + ((size_t)(bh * 512 + r0 + 64)) * 64, 64, Ks + (cur ^ 1) * 4096, w, lane);
      stage_tile_swz(Vtg + (size_t)bh * 64 * 512 + r0 + 64, 512, Vts + (cur ^ 1) * 4096, w, lane);
    } else {
      stage_tile_swz(IKg + (size_t)bh * 4096, 64, Ks, w, lane);
      stage_tile_swz(IVtg + (size_t)bh * 4096, 64, Vts, w, lane);
    }
    bf16x4 bnext[4];
    if (rt < 7) {
      const unsigned short* bt = btbase + ((size_t)(rt + 1) << 12);
      #pragma unroll
      for (int ns = 0; ns < 4; ++ns)
        bnext[ns] = *(const bf16x4*)(bt + (w * 4 + ns) * 256 + lane * 4);
    }

    const unsigned short* Kc = Ks + cur * 4096;
    const unsigned short* Vc = Vts + cur * 4096;

    f32x4 sacc[4];
    #pragma unroll
    for (int ns = 0; ns < 4; ++ns) sacc[ns] = (f32x4){0.f, 0.f, 0.f, 0.f};
    __builtin_amdgcn_s_setprio(1);
    #pragma unroll
    for (int kc = 0; kc < 2; ++kc)
      #pragma unroll
      for (int ns = 0; ns < 4; ++ns) {
        bf16x8 kb = read_swz(Kc, ns * 16 + lc, kc * 64 + lg * 16);
        sacc[ns] = mfma16(qa[kc], kb, sacc[ns]);
      }
    __builtin_amdgcn_s_setprio(0);
    float sv[4][4];
    #pragma unroll
    for (int ns = 0; ns < 4; ++ns)
      #pragma unroll
      for (int i = 0; i < 4; ++i)
        sv[ns][i] = fmaf(sacc[ns][i], C2, bf2f((unsigned short)brow[ns][i]));

    float mt[4];
    #pragma unroll
    for (int i = 0; i < 4; ++i)
      mt[i] = fmaxf(fmaxf(sv[0][i], sv[1][i]), fmaxf(sv[2][i], sv[3][i]));
    bool need = false;
    #pragma unroll
    for (int i = 0; i < 4; ++i) need = need || (mt[i] > mrun[i] + DEFER_THR);
    if (__any(need)) {
      #pragma unroll
      for (int i = 0; i < 4; ++i) {
        float m_ = mt[i];
        #pragma unroll
        for (int m = 1; m <= 8; m <<= 1) m_ = fmaxf(m_, __shfl_xor(m_, m));
        const float mnew = fmaxf(mrun[i], m_);
        const float fr = exp2f(mrun[i] - mnew);
        mrun[i] = mnew;
        lrun[i] *= fr;
        #pragma unroll
        for (int ds = 0; ds < 4; ++ds) oacc[ds][i] *= fr;
      }
    }
    #pragma unroll
    for (int ns = 0; ns < 4; ++ns)
      #pragma unroll
      for (int i = 0; i < 4; ++i)
        sv[ns][i] = exp2f(sv[ns][i] - mrun[i]);
    #pragma unroll
    for (int ns = 0; ns < 4; ++ns)
      #pragma unroll
      for (int i = 0; i < 4; ++i) {
        const int row = w * 16 + lg * 4 + i;
        const int cb = (ns * 16 + lc) * 2;
        *(unsigned short*)((char*)Ps + row * 128 + (cb ^ ((row & 7) << 4))) = f2bf(sv[ns][i]);
      }
    f32x4 lsum = (f32x4){0.f, 0.f, 0.f, 0.f};
    __builtin_amdgcn_s_setprio(1);
    #pragma unroll
    for (int kc = 0; kc < 2; ++kc) {
      bf16x8 pa = read_swz(Ps, w * 16 + lc, kc * 64 + lg * 16);
      lsum = mfma16(pa, ONES, lsum);
      #pragma unroll
      for (int ds = 0; ds < 4; ++ds) {
        bf16x8 vb = read_swz(Vc, ds * 16 + lc, kc * 64 + lg * 16);
        oacc[ds] = mfma16(pa, vb, oacc[ds]);
      }
    }
    __builtin_amdgcn_s_setprio(0);
    #pragma unroll
    for (int i = 0; i < 4; ++i) lrun[i] += lsum[i];
    if (rt < 7) {
      #pragma unroll
      for (int ns = 0; ns < 4; ++ns) brow[ns] = bnext[ns];
    }
  }

  // ---- instruct branch ----
  {
    __syncthreads();
    f32x4 sacc[4];
    #pragma unroll
    for (int ns = 0; ns < 4; ++ns) sacc[ns] = (f32x4){0.f, 0.f, 0.f, 0.f};
    #pragma unroll
    for (int kc = 0; kc < 2; ++kc)
      #pragma unroll
      for (int ns = 0; ns < 4; ++ns) {
        bf16x8 kb = read_swz(Ks, ns * 16 + lc, kc * 64 + lg * 16);
        sacc[ns] = mfma16(qa[kc], kb, sacc[ns]);
      }
    float sv[4][4];
    #pragma unroll
    for (int ns = 0; ns < 4; ++ns) {
      const float mk2 = imask[b * SIN + ns * 16 + lc] * L2E;
      #pragma unroll
      for (int i = 0; i < 4; ++i) sv[ns][i] = fmaf(sacc[ns][i], C2, mk2);
    }
    #pragma unroll
    for (int i = 0; i < 4; ++i) {
      float mt = fmaxf(fmaxf(sv[0][i], sv[1][i]), fmaxf(sv[2][i], sv[3][i]));
      #pragma unroll
      for (int m = 1; m <= 8; m <<= 1) mt = fmaxf(mt, __shfl_xor(mt, m));
      #pragma unroll
      for (int ns = 0; ns < 4; ++ns) sv[ns][i] = exp2f(sv[ns][i] - mt);
    }
    #pragma unroll
    for (int ns = 0; ns < 4; ++ns)
      #pragma unroll
      for (int i = 0; i < 4; ++i) {
        const int row = w * 16 + lg * 4 + i;
        const int cb = (ns * 16 + lc) * 2;
        *(unsigned short*)((char*)Ps + row * 128 + (cb ^ ((row & 7) << 4))) = f2bf(sv[ns][i]);
      }
    f32x4 iacc[4];
    #pragma unroll
    for (int ds = 0; ds < 4; ++ds) iacc[ds] = (f32x4){0.f, 0.f, 0.f, 0.f};
    f32x4 isum = (f32x4){0.f, 0.f, 0.f, 0.f};
    #pragma unroll
    for (int kc = 0; kc < 2; ++kc) {
      bf16x8 pa = read_swz(Ps, w * 16 + lc, kc * 64 + lg * 16);
      isum = mfma16(pa, ONES, isum);
      #pragma unroll
      for (int ds = 0; ds < 4; ++ds) {
        bf16x8 vb = read_swz(Vts, ds * 16 + lc, kc * 64 + lg * 16);
        iacc[ds] = mfma16(pa, vb, iacc[ds]);
      }
    }
    const float tg = tanhf(gate[h]);
    #pragma unroll
    for (int ds = 0; ds < 4; ++ds)
      #pragma unroll
      for (int i = 0; i < 4; ++i) {
        const int li = w * 16 + lg * 4 + i;
        const float val = oacc[ds][i] / lrun[i] + tg * (iacc[ds][i] / isum[i]);
        out[(size_t)(b * SEQ + l0 + li) * 1024 + h * 64 + ds * 16 + lc] = val;
      }
  }
}

// ---------------- launch ----------------

extern "C" void kernel_launch(void* const* d_in, const int* in_sizes, int n_in,
                              void* d_out, int out_size, void* d_ws, size_t ws_size,
                              hipStream_t stream) {
  (void)in_sizes; (void)n_in; (void)out_size; (void)ws_size;
  const float* hs    = (const float*)d_in[0];
  const float* ihs   = (const float*)d_in[1];
  const float* mask  = (const float*)d_in[2];
  const float* imask = (const float*)d_in[3];
  const float* Wq    = (const float*)d_in[4];
  const float* bq    = (const float*)d_in[5];
  const float* Wk    = (const float*)d_in[6];
  const float* bk    = (const float*)d_in[7];
  const float* Wv    = (const float*)d_in[8];
  const float* bv    = (const float*)d_in[9];
  const float* de    = (const float*)d_in[10];
  const float* gate  = (const float*)d_in[11];
  float* out = (float*)d_out;

  char* ws = (char*)d_ws;
  size_t off = 0;
  auto alloc = [&](size_t bytes) -> void* {
    void* p = ws + off;
    off += (bytes + 255) & ~(size_t)255;
    return p;
  };
  unsigned short* X    = (unsigned short*)alloc((size_t)4608 * 1024 * 2);
  unsigned short* Wt   = (unsigned short*)alloc((size_t)3072 * 1024 * 2);
  unsigned short* E    = (unsigned short*)alloc((size_t)1024 * 64 * 2);
  unsigned short* Qb   = (unsigned short*)alloc((size_t)8 * 16 * 512 * 64 * 2);
  unsigned short* Kb   = (unsigned short*)alloc((size_t)8 * 16 * 512 * 64 * 2);
  unsigned short* Vtb  = (unsigned short*)alloc((size_t)8 * 16 * 64 * 512 * 2);
  unsigned short* IKb  = (unsigned short*)alloc((size_t)8 * 16 * 64 * 64 * 2);
  unsigned short* IVtb = (unsigned short*)alloc((size_t)8 * 16 * 64 * 64 * 2);
  unsigned short* Bias = (unsigned short*)alloc((size_t)128 * 64 * 4096 * 2);  // 64 MiB

  k_convert_all<<<5440, 256, 0, stream>>>(hs, ihs, de, Wq, Wk, Wv, X, E, Wt);
  k_gemm<<<dim3(12, 18), 512, 0, stream>>>(X, Wt, bq, bk, bv, Qb, Kb, Vtb, IKb, IVtb);
  k_bias<<<dim3(8, 8, 128), 256, 0, stream>>>(Qb, Kb, E, mask, Bias);
  k_attn<<<dim3(8, 16, 8), 256, 0, stream>>>(Qb, Kb, Vtb, IKb, IVtb, Bias, imask, gate, out);
}

// Round 24
// 128.640 us; speedup vs baseline: 1.0637x; 1.0081x over previous
//
#include <hip/hip_runtime.h>

#define NH 16
#define DH 64
#define SEQ 512
#define SIN 64
#define NBATCH 8

#define L2E 1.4426950408889634f          // log2(e)
#define C2  0.18033688011112043f         // 0.125 * log2(e)
#define DEFER_THR 11.5412435f            // 8 * log2(e)

typedef short bf16x8 __attribute__((ext_vector_type(8)));
typedef short bf16x4 __attribute__((ext_vector_type(4)));
typedef float f32x4 __attribute__((ext_vector_type(4)));

__device__ __forceinline__ unsigned short f2bf(float f) {
  union { float f; unsigned u; } v; v.f = f;
  unsigned r = v.u + 0x7FFFu + ((v.u >> 16) & 1u);
  return (unsigned short)(r >> 16);
}
__device__ __forceinline__ float bf2f(unsigned short b) {
  union { unsigned u; float f; } v; v.u = ((unsigned)b) << 16;
  return v.f;
}
__device__ __forceinline__ f32x4 mfma16(bf16x8 a, bf16x8 b, f32x4 c) {
  return __builtin_amdgcn_mfma_f32_16x16x32_bf16(a, b, c, 0, 0, 0);
}
__device__ __forceinline__ void gload_lds16(const unsigned short* g, unsigned short* l) {
  __builtin_amdgcn_global_load_lds((const __attribute__((address_space(1))) void*)g,
                                   (__attribute__((address_space(3))) void*)l, 16, 0, 0);
}

// 64x64 bf16 tile in LDS, logical [64][64], physical byte swizzle
// phys = row*128 + (colbyte ^ ((row&7)<<4)); staged with pre-swizzled global src.
__device__ __forceinline__ void stage_tile_swz(const unsigned short* g, int gstride,
                                               unsigned short* lds, int w, int lane) {
  #pragma unroll
  for (int c = 0; c < 2; ++c) {
    const int row = w * 16 + c * 8 + (lane >> 3);
    const int cb = ((lane & 7) ^ (lane >> 3)) << 4;
    gload_lds16(g + (size_t)row * gstride + (cb >> 1),
                lds + (w * 16 + c * 8) * 64);
  }
}
__device__ __forceinline__ bf16x8 read_swz(const unsigned short* lds, int row, int colbyte) {
  return *(const bf16x8*)((const char*)(lds + row * 64) + (colbyte ^ ((row & 7) << 4)));
}
// same swizzle for 128-byte rows (BK=64 staging in k_gemm)
__device__ __forceinline__ bf16x8 read_swz128(const unsigned short* lds, int row, int colbyte) {
  return *(const bf16x8*)((const char*)lds + row * 128 + (colbyte ^ ((row & 7) << 4)));
}

// ---------------- merged convert kernel ----------------
__global__ __launch_bounds__(256) void k_convert_all(const float* __restrict__ hs,
                                                     const float* __restrict__ ihs,
                                                     const float* __restrict__ de,
                                                     const float* __restrict__ Wq,
                                                     const float* __restrict__ Wk,
                                                     const float* __restrict__ Wv,
                                                     unsigned short* __restrict__ X,
                                                     unsigned short* __restrict__ E,
                                                     unsigned short* __restrict__ Wt) {
  __shared__ float t[64][65];
  const int bx = blockIdx.x, tid = threadIdx.x;
  if (bx < 4608) {
    int idx = bx * 256 + tid;
    float4 v;
    if (idx < 1048576) v = ((const float4*)hs)[idx];
    else               v = ((const float4*)ihs)[idx - 1048576];
    ushort4 o; o.x = f2bf(v.x); o.y = f2bf(v.y); o.z = f2bf(v.z); o.w = f2bf(v.w);
    ((ushort4*)X)[idx] = o;
  } else if (bx < 5376) {
    const int wb = bx - 4608;
    const int z = wb >> 8, rem = wb & 255;
    const float* W = (z == 0) ? Wq : (z == 1) ? Wk : Wv;
    const int n0 = (rem & 15) * 64, k0 = (rem >> 4) * 64;
    #pragma unroll
    for (int q = 0; q < 4; ++q) {
      int s = q * 256 + tid;
      int r = s >> 4, c4 = s & 15;
      float4 v = *(const float4*)(W + (size_t)(k0 + r) * 1024 + n0 + c4 * 4);
      t[r][c4 * 4 + 0] = v.x; t[r][c4 * 4 + 1] = v.y;
      t[r][c4 * 4 + 2] = v.z; t[r][c4 * 4 + 3] = v.w;
    }
    __syncthreads();
    #pragma unroll
    for (int q = 0; q < 4; ++q) {
      int s = q * 256 + tid;
      int rn = s >> 4, c4 = s & 15;
      ushort4 o;
      o.x = f2bf(t[c4 * 4 + 0][rn]); o.y = f2bf(t[c4 * 4 + 1][rn]);
      o.z = f2bf(t[c4 * 4 + 2][rn]); o.w = f2bf(t[c4 * 4 + 3][rn]);
      *(ushort4*)(Wt + ((size_t)(z << 10) + n0 + rn) * 1024 + k0 + c4 * 4) = o;
    }
  } else {
    int idx = (bx - 5376) * 256 + tid;
    ushort4 o;
    if (idx < 16368) {
      float4 v = ((const float4*)de)[idx];
      o.x = f2bf(v.x); o.y = f2bf(v.y); o.z = f2bf(v.z); o.w = f2bf(v.w);
    } else { o.x = 0; o.y = 0; o.z = 0; o.w = 0; }
    ((ushort4*)E)[idx] = o;
  }
}

// ---------------- fused QKV GEMM (256x256, 8 waves, BK=64, swizzled staging) ----------------
// XCD-swizzled block mapping: 216 blocks = 8 XCDs x 27 (bijective chunked).
__global__ __launch_bounds__(512) void k_gemm(const unsigned short* __restrict__ X,
                                              const unsigned short* __restrict__ Wt,
                                              const float* __restrict__ bq,
                                              const float* __restrict__ bk,
                                              const float* __restrict__ bv,
                                              unsigned short* __restrict__ Q,
                                              unsigned short* __restrict__ K,
                                              unsigned short* __restrict__ Vt,
                                              unsigned short* __restrict__ IK,
                                              unsigned short* __restrict__ IVt) {
  __shared__ unsigned short smem[65536];   // A[2]@0 (2x32KB), B[2]@32768; epilogue reuses all
  const int tid = threadIdx.x, lane = tid & 63, w = tid >> 6;
  const int lg = lane >> 4, lc = lane & 15;
  const int bid = blockIdx.x + 12 * blockIdx.y;
  const int swz = (bid & 7) * 27 + (bid >> 3);          // 216 = 8*27
  const int m0 = (swz / 12) * 256, n0 = (swz % 12) * 256;
  const int wr = w >> 2, wc = w & 3;
  const int which = n0 >> 10;
  const int h0 = (n0 & 1023) >> 6;
  const float* barr = (which == 0) ? bq : (which == 1) ? bk : bv;

  f32x4 acc[8][4];
  #pragma unroll
  for (int i = 0; i < 8; ++i)
    #pragma unroll
    for (int j = 0; j < 4; ++j) acc[i][j] = (f32x4){0.f, 0.f, 0.f, 0.f};

  const unsigned short* ap[4];
  const unsigned short* bp[4];
  #pragma unroll
  for (int q = 0; q < 4; ++q) {
    const int c = (w * 4 + q) * 64 + lane;
    const int row = c >> 3, cc = c & 7;
    const int sc = (cc ^ (row & 7)) * 8;
    ap[q] = X  + (size_t)(m0 + row) * 1024 + sc;
    bp[q] = Wt + (size_t)(n0 + row) * 1024 + sc;
  }

  #define STAGE(bi)                                                        \
    {                                                                      \
      _Pragma("unroll")                                                    \
      for (int q_ = 0; q_ < 4; ++q_) {                                     \
        gload_lds16(ap[q_], smem + (bi) * 16384 + ((w * 4 + q_) * 64) * 8);\
        gload_lds16(bp[q_], smem + 32768 + (bi) * 16384 + ((w * 4 + q_) * 64) * 8); \
        ap[q_] += 64; bp[q_] += 64;                                        \
      }                                                                    \
    }

  STAGE(0);
  int cur = 0;
  for (int kt = 0; kt < 16; ++kt) {
    __syncthreads();
    if (kt + 1 < 16) STAGE(cur ^ 1);
    const unsigned short* A = smem + cur * 16384;
    const unsigned short* B = smem + 32768 + cur * 16384;
    #pragma unroll
    for (int kc = 0; kc < 2; ++kc) {
      bf16x8 af[8], bfr[4];
      #pragma unroll
      for (int i = 0; i < 8; ++i)
        af[i] = read_swz128(A, wr * 128 + i * 16 + lc, kc * 64 + lg * 16);
      #pragma unroll
      for (int j = 0; j < 4; ++j)
        bfr[j] = read_swz128(B, wc * 64 + j * 16 + lc, kc * 64 + lg * 16);
      __builtin_amdgcn_s_setprio(1);
      #pragma unroll
      for (int i = 0; i < 8; ++i)
        #pragma unroll
        for (int j = 0; j < 4; ++j)
          acc[i][j] = mfma16(af[i], bfr[j], acc[i][j]);
      __builtin_amdgcn_s_setprio(0);
    }
    cur ^= 1;
  }
  #undef STAGE

  __syncthreads();
  {
    char* Cs = (char*)smem;
    #pragma unroll
    for (int j = 0; j < 4; ++j) {
      const float bias = barr[(n0 & 1023) + wc * 64 + j * 16 + lc];
      #pragma unroll
      for (int i = 0; i < 8; ++i)
        #pragma unroll
        for (int ii = 0; ii < 4; ++ii) {
          int row = wr * 128 + i * 16 + lg * 4 + ii;
          int col = wc * 64 + j * 16 + lc;
          if (which == 2) { int t = row; row = col; col = t; }
          *(unsigned short*)(Cs + row * 512 + ((col * 2) ^ (((row >> 2) & 31) << 4))) =
              f2bf(acc[i][j][ii] + bias);
        }
    }
  }
  __syncthreads();
  {
    const char* Cs = (const char*)smem;
    const int row = tid >> 1;
    #pragma unroll
    for (int rnd = 0; rnd < 2; ++rnd) {
      const int q = (tid & 1) + rnd * 2;
      uint4 cvec[8];
      #pragma unroll
      for (int c8 = 0; c8 < 8; ++c8)
        cvec[c8] = *(const uint4*)(Cs + row * 512 +
                                   ((q * 128 + c8 * 16) ^ (((row >> 2) & 31) << 4)));
      unsigned short* dst = nullptr;
      if (which != 2) {
        const int gm = m0 + row, hh = h0 + q;
        if (gm < 4096) {
          const int bb = gm >> 9, ss = gm & 511;
          unsigned short* base = (which == 0) ? Q : K;
          dst = base + (((size_t)(bb * NH + hh) * 512 + ss) << 6);
        } else if (which == 1) {
          const int mi = gm - 4096, bb = mi >> 6, si = mi & 63;
          dst = IK + (((size_t)(bb * NH + hh) * 64 + si) << 6);
        }
      } else {
        const int dd = row, hh = h0 + (dd >> 6), ddl = dd & 63;
        const int gm0 = m0 + q * 64;
        if (gm0 < 4096) {
          const int bb = gm0 >> 9, ss0 = gm0 & 511;
          dst = Vt + ((size_t)(bb * NH + hh) * 64 + ddl) * 512 + ss0;
        } else {
          const int mi0 = gm0 - 4096, bb = mi0 >> 6;
          dst = IVt + (((size_t)(bb * NH + hh) * 64 + ddl) << 6);
        }
      }
      if (dst) {
        #pragma unroll
        for (int c8 = 0; c8 < 8; ++c8)
          *(uint4*)(dst + c8 * 8) = cvec[c8];
      }
    }
  }
}

// ---------------- bias tile kernel (v4 + XCD-grouped decode) ----------------
// Tables stored [128 u][64 row], physical col = row ^ ((u&7)<<3).  All 64
// (rt,lt) blocks of one bh land on XCD bh%8 -> Q/K stay L2-resident
// (16 bh-groups x 128 KB = 2 MB < 4 MB per-XCD L2).
__global__ __launch_bounds__(256) void k_bias(const unsigned short* __restrict__ Qg,
                                              const unsigned short* __restrict__ Kg,
                                              const unsigned short* __restrict__ Eg,
                                              const float* __restrict__ mask,
                                              unsigned short* __restrict__ Bias) {
  const int fb = blockIdx.x + 8 * (blockIdx.y + 8 * blockIdx.z);   // [0,8192)
  const int xcd = fb & 7, slot = fb >> 3;
  const int bh = xcd + 8 * (slot >> 6);
  const int rt = slot & 7, lt = (slot >> 3) & 7;
  const int l0 = lt * 64, r0 = rt * 64;
  const int p0 = l0 - r0 + 448;
  const int tid = threadIdx.x, lane = tid & 63, w = tid >> 6;
  const int lg = lane >> 4, lc = lane & 15;
  const int ubase = w * 32;
  const int b = bh >> 4;

  __shared__ unsigned short smem[16384];     // 32 KB
  unsigned short* Qs  = smem;                // phase A: 8 KB
  unsigned short* Ks  = smem + 4096;         // phase A: 8 KB
  unsigned short* qdl = smem + 8192;         // 16 KB, [128][64] (persistent)
  unsigned short* kdl = smem;                // phase B: 16 KB over Qs+Ks

  stage_tile_swz(Qg + ((size_t)(bh * 512 + l0)) * 64, 64, Qs, w, lane);
  stage_tile_swz(Kg + ((size_t)(bh * 512 + r0)) * 64, 64, Ks, w, lane);

  bf16x8 eb[2][2];
  #pragma unroll
  for (int ns = 0; ns < 2; ++ns) {
    const int u = ubase + ns * 16 + lc;
    const unsigned short* ep = Eg + (size_t)(p0 + u) * 64 + lg * 8;
    eb[ns][0] = *(const bf16x8*)(ep);
    eb[ns][1] = *(const bf16x8*)(ep + 32);
  }
  __syncthreads();    // staging complete

  f32x4 da[4][2];
  // qd: MFMAs over Qs -> qdl (disjoint region)
  #pragma unroll
  for (int ms = 0; ms < 4; ++ms) { da[ms][0] = (f32x4){0,0,0,0}; da[ms][1] = (f32x4){0,0,0,0}; }
  #pragma unroll
  for (int kc = 0; kc < 2; ++kc)
    #pragma unroll
    for (int ms = 0; ms < 4; ++ms) {
      bf16x8 a = read_swz(Qs, ms * 16 + lc, kc * 64 + lg * 16);
      da[ms][0] = mfma16(a, eb[0][kc], da[ms][0]);
      da[ms][1] = mfma16(a, eb[1][kc], da[ms][1]);
    }
  #pragma unroll
  for (int ns = 0; ns < 2; ++ns) {
    const int u = ubase + ns * 16 + lc;
    const int k = (u & 7) << 3;
    #pragma unroll
    for (int ms = 0; ms < 4; ++ms) {
      ushort4 o;
      o.x = f2bf(da[ms][ns][0]); o.y = f2bf(da[ms][ns][1]);
      o.z = f2bf(da[ms][ns][2]); o.w = f2bf(da[ms][ns][3]);
      *(ushort4*)(qdl + u * 64 + ((ms * 16 + lg * 4) ^ k)) = o;
    }
  }
  // kd: MFMAs over Ks, held in regs across the barrier
  #pragma unroll
  for (int ms = 0; ms < 4; ++ms) { da[ms][0] = (f32x4){0,0,0,0}; da[ms][1] = (f32x4){0,0,0,0}; }
  #pragma unroll
  for (int kc = 0; kc < 2; ++kc)
    #pragma unroll
    for (int ms = 0; ms < 4; ++ms) {
      bf16x8 a = read_swz(Ks, ms * 16 + lc, kc * 64 + lg * 16);
      da[ms][0] = mfma16(a, eb[0][kc], da[ms][0]);
      da[ms][1] = mfma16(a, eb[1][kc], da[ms][1]);
    }
  __syncthreads();    // Qs/Ks reads done; safe to overwrite with kdl
  #pragma unroll
  for (int ns = 0; ns < 2; ++ns) {
    const int u = ubase + ns * 16 + lc;
    const int k = (u & 7) << 3;
    #pragma unroll
    for (int ms = 0; ms < 4; ++ms) {
      ushort4 o;
      o.x = f2bf(da[ms][ns][0]); o.y = f2bf(da[ms][ns][1]);
      o.z = f2bf(da[ms][ns][2]); o.w = f2bf(da[ms][ns][3]);
      *(ushort4*)(kdl + u * 64 + ((ms * 16 + lg * 4) ^ k)) = o;
    }
  }
  __syncthreads();    // tables visible

  {
    unsigned short* dst = Bias + (((size_t)(bh * 64 + lt * 8 + rt)) << 12);
    #pragma unroll
    for (int ns = 0; ns < 4; ++ns) {
      const int ri = ns * 16 + lc;
      const float mk2 = mask[b * SEQ + r0 + ri] * L2E;
      ushort4 o;
      #pragma unroll
      for (int i = 0; i < 4; ++i) {
        const int li = w * 16 + lg * 4 + i;
        const int uq = li - ri + 63;
        const int k = (uq & 7) << 3;
        const float qv = bf2f(qdl[uq * 64 + (li ^ k)]);
        const float kv = bf2f(kdl[uq * 64 + (ri ^ k)]);
        const unsigned short val = f2bf((qv + kv) * C2 + mk2);
        if (i == 0) o.x = val; else if (i == 1) o.y = val;
        else if (i == 2) o.z = val; else o.w = val;
      }
      *(ushort4*)(dst + (w * 4 + ns) * 256 + lane * 4) = o;
    }
  }
}

// ---------------- fused attention ----------------
// flash, dbuf K/V, reg bias, exp2 softmax, lazy-max defer, ones-MFMA denominators.
// XCD-grouped block decode: the 8 lt-tiles of one (b,h) share an XCD so its
// K/V stays L2-resident (16 groups x 160 KB = 2.6 MB < 4 MB per-XCD L2).
__global__ __launch_bounds__(256) void k_attn(const unsigned short* __restrict__ Qg,
                                              const unsigned short* __restrict__ Kg,
                                              const unsigned short* __restrict__ Vtg,
                                              const unsigned short* __restrict__ IKg,
                                              const unsigned short* __restrict__ IVtg,
                                              const unsigned short* __restrict__ Bias,
                                              const float* __restrict__ imask,
                                              const float* __restrict__ gate,
                                              float* __restrict__ out) {
  const int fb = blockIdx.x + 8 * (blockIdx.y + 16 * blockIdx.z);  // [0,1024)
  const int xcd = fb & 7, slot = fb >> 3;
  const int gidx = xcd + 8 * (slot >> 3);   // (b,h) group on XCD gidx%8
  const int lt = slot & 7;
  const int h = gidx & 15, b = gidx >> 4;
  const int l0 = lt * 64;
  const int tid = threadIdx.x;
  const int lane = tid & 63, w = tid >> 6;
  const int lg = lane >> 4, lc = lane & 15;
  const int bh = b * NH + h;
  const short ob = (short)0x3F80;
  const bf16x8 ONES = {ob, ob, ob, ob, ob, ob, ob, ob};

  __shared__ unsigned short Ks[2 * 64 * 64];
  __shared__ unsigned short Vts[2 * 64 * 64];
  __shared__ unsigned short Ps[64 * 64];

  bf16x8 qa[2];
  {
    const unsigned short* qrow = Qg + ((size_t)(bh * 512 + l0 + w * 16 + lc)) * 64;
    qa[0] = *(const bf16x8*)(qrow + lg * 8);
    qa[1] = *(const bf16x8*)(qrow + 32 + lg * 8);
  }

  f32x4 oacc[4];
  #pragma unroll
  for (int i = 0; i < 4; ++i) oacc[i] = (f32x4){0.f, 0.f, 0.f, 0.f};
  float mrun[4], lrun[4];
  #pragma unroll
  for (int i = 0; i < 4; ++i) { mrun[i] = -3.0e38f; lrun[i] = 0.f; }

  stage_tile_swz(Kg + ((size_t)(bh * 512)) * 64, 64, Ks, w, lane);
  stage_tile_swz(Vtg + (size_t)bh * 64 * 512, 512, Vts, w, lane);
  const unsigned short* btbase = Bias + (((size_t)(bh * 64 + lt * 8)) << 12);
  bf16x4 brow[4];
  #pragma unroll
  for (int ns = 0; ns < 4; ++ns)
    brow[ns] = *(const bf16x4*)(btbase + (w * 4 + ns) * 256 + lane * 4);

  for (int rt = 0; rt < 8; ++rt) {
    const int r0 = rt * 64;
    const int cur = rt & 1;
    __syncthreads();

    if (rt < 7) {
      stage_tile_swz(Kg + ((size_t)(bh * 512 + r0 + 64)) * 64, 64, Ks + (cur ^ 1) * 4096, w, lane);
      stage_tile_swz(Vtg + (size_t)bh * 64 * 512 + r0 + 64, 512, Vts + (cur ^ 1) * 4096, w, lane);
    } else {
      stage_tile_swz(IKg + (size_t)bh * 4096, 64, Ks, w, lane);
      stage_tile_swz(IVtg + (size_t)bh * 4096, 64, Vts, w, lane);
    }
    bf16x4 bnext[4];
    if (rt < 7) {
      const unsigned short* bt = btbase + ((size_t)(rt + 1) << 12);
      #pragma unroll
      for (int ns = 0; ns < 4; ++ns)
        bnext[ns] = *(const bf16x4*)(bt + (w * 4 + ns) * 256 + lane * 4);
    }

    const unsigned short* Kc = Ks + cur * 4096;
    const unsigned short* Vc = Vts + cur * 4096;

    f32x4 sacc[4];
    #pragma unroll
    for (int ns = 0; ns < 4; ++ns) sacc[ns] = (f32x4){0.f, 0.f, 0.f, 0.f};
    __builtin_amdgcn_s_setprio(1);
    #pragma unroll
    for (int kc = 0; kc < 2; ++kc)
      #pragma unroll
      for (int ns = 0; ns < 4; ++ns) {
        bf16x8 kb = read_swz(Kc, ns * 16 + lc, kc * 64 + lg * 16);
        sacc[ns] = mfma16(qa[kc], kb, sacc[ns]);
      }
    __builtin_amdgcn_s_setprio(0);
    float sv[4][4];
    #pragma unroll
    for (int ns = 0; ns < 4; ++ns)
      #pragma unroll
      for (int i = 0; i < 4; ++i)
        sv[ns][i] = fmaf(sacc[ns][i], C2, bf2f((unsigned short)brow[ns][i]));

    float mt[4];
    #pragma unroll
    for (int i = 0; i < 4; ++i)
      mt[i] = fmaxf(fmaxf(sv[0][i], sv[1][i]), fmaxf(sv[2][i], sv[3][i]));
    bool need = false;
    #pragma unroll
    for (int i = 0; i < 4; ++i) need = need || (mt[i] > mrun[i] + DEFER_THR);
    if (__any(need)) {
      #pragma unroll
      for (int i = 0; i < 4; ++i) {
        float m_ = mt[i];
        #pragma unroll
        for (int m = 1; m <= 8; m <<= 1) m_ = fmaxf(m_, __shfl_xor(m_, m));
        const float mnew = fmaxf(mrun[i], m_);
        const float fr = exp2f(mrun[i] - mnew);
        mrun[i] = mnew;
        lrun[i] *= fr;
        #pragma unroll
        for (int ds = 0; ds < 4; ++ds) oacc[ds][i] *= fr;
      }
    }
    #pragma unroll
    for (int ns = 0; ns < 4; ++ns)
      #pragma unroll
      for (int i = 0; i < 4; ++i)
        sv[ns][i] = exp2f(sv[ns][i] - mrun[i]);
    #pragma unroll
    for (int ns = 0; ns < 4; ++ns)
      #pragma unroll
      for (int i = 0; i < 4; ++i) {
        const int row = w * 16 + lg * 4 + i;
        const int cb = (ns * 16 + lc) * 2;
        *(unsigned short*)((char*)Ps + row * 128 + (cb ^ ((row & 7) << 4))) = f2bf(sv[ns][i]);
      }
    f32x4 lsum = (f32x4){0.f, 0.f, 0.f, 0.f};
    __builtin_amdgcn_s_setprio(1);
    #pragma unroll
    for (int kc = 0; kc < 2; ++kc) {
      bf16x8 pa = read_swz(Ps, w * 16 + lc, kc * 64 + lg * 16);
      lsum = mfma16(pa, ONES, lsum);
      #pragma unroll
      for (int ds = 0; ds < 4; ++ds) {
        bf16x8 vb = read_swz(Vc, ds * 16 + lc, kc * 64 + lg * 16);
        oacc[ds] = mfma16(pa, vb, oacc[ds]);
      }
    }
    __builtin_amdgcn_s_setprio(0);
    #pragma unroll
    for (int i = 0; i < 4; ++i) lrun[i] += lsum[i];
    if (rt < 7) {
      #pragma unroll
      for (int ns = 0; ns < 4; ++ns) brow[ns] = bnext[ns];
    }
  }

  // ---- instruct branch ----
  {
    __syncthreads();
    f32x4 sacc[4];
    #pragma unroll
    for (int ns = 0; ns < 4; ++ns) sacc[ns] = (f32x4){0.f, 0.f, 0.f, 0.f};
    #pragma unroll
    for (int kc = 0; kc < 2; ++kc)
      #pragma unroll
      for (int ns = 0; ns < 4; ++ns) {
        bf16x8 kb = read_swz(Ks, ns * 16 + lc, kc * 64 + lg * 16);
        sacc[ns] = mfma16(qa[kc], kb, sacc[ns]);
      }
    float sv[4][4];
    #pragma unroll
    for (int ns = 0; ns < 4; ++ns) {
      const float mk2 = imask[b * SIN + ns * 16 + lc] * L2E;
      #pragma unroll
      for (int i = 0; i < 4; ++i) sv[ns][i] = fmaf(sacc[ns][i], C2, mk2);
    }
    #pragma unroll
    for (int i = 0; i < 4; ++i) {
      float mt = fmaxf(fmaxf(sv[0][i], sv[1][i]), fmaxf(sv[2][i], sv[3][i]));
      #pragma unroll
      for (int m = 1; m <= 8; m <<= 1) mt = fmaxf(mt, __shfl_xor(mt, m));
      #pragma unroll
      for (int ns = 0; ns < 4; ++ns) sv[ns][i] = exp2f(sv[ns][i] - mt);
    }
    #pragma unroll
    for (int ns = 0; ns < 4; ++ns)
      #pragma unroll
      for (int i = 0; i < 4; ++i) {
        const int row = w * 16 + lg * 4 + i;
        const int cb = (ns * 16 + lc) * 2;
        *(unsigned short*)((char*)Ps + row * 128 + (cb ^ ((row & 7) << 4))) = f2bf(sv[ns][i]);
      }
    f32x4 iacc[4];
    #pragma unroll
    for (int ds = 0; ds < 4; ++ds) iacc[ds] = (f32x4){0.f, 0.f, 0.f, 0.f};
    f32x4 isum = (f32x4){0.f, 0.f, 0.f, 0.f};
    #pragma unroll
    for (int kc = 0; kc < 2; ++kc) {
      bf16x8 pa = read_swz(Ps, w * 16 + lc, kc * 64 + lg * 16);
      isum = mfma16(pa, ONES, isum);
      #pragma unroll
      for (int ds = 0; ds < 4; ++ds) {
        bf16x8 vb = read_swz(Vts, ds * 16 + lc, kc * 64 + lg * 16);
        iacc[ds] = mfma16(pa, vb, iacc[ds]);
      }
    }
    const float tg = tanhf(gate[h]);
    #pragma unroll
    for (int ds = 0; ds < 4; ++ds)
      #pragma unroll
      for (int i = 0; i < 4; ++i) {
        const int li = w * 16 + lg * 4 + i;
        const float val = oacc[ds][i] / lrun[i] + tg * (iacc[ds][i] / isum[i]);
        out[(size_t)(b * SEQ + l0 + li) * 1024 + h * 64 + ds * 16 + lc] = val;
      }
  }
}

// ---------------- launch ----------------

extern "C" void kernel_launch(void* const* d_in, const int* in_sizes, int n_in,
                              void* d_out, int out_size, void* d_ws, size_t ws_size,
                              hipStream_t stream) {
  (void)in_sizes; (void)n_in; (void)out_size; (void)ws_size;
  const float* hs    = (const float*)d_in[0];
  const float* ihs   = (const float*)d_in[1];
  const float* mask  = (const float*)d_in[2];
  const float* imask = (const float*)d_in[3];
  const float* Wq    = (const float*)d_in[4];
  const float* bq    = (const float*)d_in[5];
  const float* Wk    = (const float*)d_in[6];
  const float* bk    = (const float*)d_in[7];
  const float* Wv    = (const float*)d_in[8];
  const float* bv    = (const float*)d_in[9];
  const float* de    = (const float*)d_in[10];
  const float* gate  = (const float*)d_in[11];
  float* out = (float*)d_out;

  char* ws = (char*)d_ws;
  size_t off = 0;
  auto alloc = [&](size_t bytes) -> void* {
    void* p = ws + off;
    off += (bytes + 255) & ~(size_t)255;
    return p;
  };
  unsigned short* X    = (unsigned short*)alloc((size_t)4608 * 1024 * 2);
  unsigned short* Wt   = (unsigned short*)alloc((size_t)3072 * 1024 * 2);
  unsigned short* E    = (unsigned short*)alloc((size_t)1024 * 64 * 2);
  unsigned short* Qb   = (unsigned short*)alloc((size_t)8 * 16 * 512 * 64 * 2);
  unsigned short* Kb   = (unsigned short*)alloc((size_t)8 * 16 * 512 * 64 * 2);
  unsigned short* Vtb  = (unsigned short*)alloc((size_t)8 * 16 * 64 * 512 * 2);
  unsigned short* IKb  = (unsigned short*)alloc((size_t)8 * 16 * 64 * 64 * 2);
  unsigned short* IVtb = (unsigned short*)alloc((size_t)8 * 16 * 64 * 64 * 2);
  unsigned short* Bias = (unsigned short*)alloc((size_t)128 * 64 * 4096 * 2);  // 64 MiB

  k_convert_all<<<5440, 256, 0, stream>>>(hs, ihs, de, Wq, Wk, Wv, X, E, Wt);
  k_gemm<<<dim3(12, 18), 512, 0, stream>>>(X, Wt, bq, bk, bv, Qb, Kb, Vtb, IKb, IVtb);
  k_bias<<<dim3(8, 8, 128), 256, 0, stream>>>(Qb, Kb, E, mask, Bias);
  k_attn<<<dim3(8, 16, 8), 256, 0, stream>>>(Qb, Kb, Vtb, IKb, IVtb, Bias, imask, gate, out);
}